// Round 1
// baseline (812.340 us; speedup 1.0000x reference)
//
#include <hip/hip_runtime.h>
#include <hip/hip_bf16.h>

#define NN 100000
#define NE 1600000

typedef __attribute__((ext_vector_type(8))) short bfrag8;   // 8 bf16 (4 VGPRs) MFMA operand
typedef __attribute__((ext_vector_type(4))) float f32x4;    // MFMA accumulator
typedef __attribute__((ext_vector_type(4))) unsigned short us4;
typedef __attribute__((ext_vector_type(8))) unsigned short us8;

__device__ __forceinline__ unsigned short f2bf(float f) {
  unsigned int u = __float_as_uint(f);
  u += 0x7fffu + ((u >> 16) & 1u);   // RNE
  return (unsigned short)(u >> 16);
}

__device__ __forceinline__ f32x4 mfma16(bfrag8 a, bfrag8 b, f32x4 c) {
  return __builtin_amdgcn_mfma_f32_16x16x32_bf16(a, b, c, 0, 0, 0);
}

__device__ __forceinline__ void stage8(unsigned short* dst, const float* src) {
  float4 a = *(const float4*)src;
  float4 b = *(const float4*)(src + 4);
  us8 o;
  o[0] = f2bf(a.x); o[1] = f2bf(a.y); o[2] = f2bf(a.z); o[3] = f2bf(a.w);
  o[4] = f2bf(b.x); o[5] = f2bf(b.y); o[6] = f2bf(b.z); o[7] = f2bf(b.w);
  *(us8*)dst = o;
}

// Pack W[K][N] f32 row-major -> Wp[g][c][j] bf16 with k = g*8+j (fragment-linear)
__global__ void pack_w(const float* __restrict__ src, unsigned short* __restrict__ dst,
                       int K, int N) {
  int i = blockIdx.x * 256 + threadIdx.x;
  if (i >= K * N) return;
  int j = i & 7;
  int gc = i >> 3;        // g*N + c
  int c = gc % N;
  int g = gc / N;
  dst[i] = f2bf(src[(g * 8 + j) * N + c]);
}

// ---------------- Edge kernel: 64 edges/block, 4 waves, wave owns 16 edges ----------------
__global__ __launch_bounds__(256, 2) void edge_kernel(
    const float* __restrict__ bonds, const int* __restrict__ a1p, const int* __restrict__ a2p,
    const float* __restrict__ atoms,
    const float* __restrict__ be1, const float* __restrict__ be2, const float* __restrict__ be3,
    const unsigned short* __restrict__ wpack,
    float* __restrict__ new_bonds, float* __restrict__ sums, float* __restrict__ counts) {
  __shared__ unsigned short sW[22528];          // We1p[12288] We2p[8192] We3p[2048]
  __shared__ float sB1[128], sB2[64], sB3[32];
  __shared__ unsigned short sX[64 * 104];       // x tile [64][96] pad->104; reused as h2 [64][72]
  __shared__ unsigned short sH1[64 * 136];      // h1 tile [64][128] pad->136

  const int tid = threadIdx.x;
  const int lane = tid & 63, wv = tid >> 6;
  const int e0 = blockIdx.x * 64;

  // stage weights (45056B = 2816 uint4 = 11*256)
  {
    const uint4* src = (const uint4*)wpack;
    uint4* dst = (uint4*)sW;
#pragma unroll
    for (int i = 0; i < 11; ++i) dst[tid + i * 256] = src[tid + i * 256];
  }
  if (tid < 128) sB1[tid] = be1[tid];
  if (tid < 64) sB2[tid] = be2[tid];
  if (tid < 32) sB3[tid] = be3[tid];

  // stage x tile: 4 threads per edge, 8 f32 per source each
  {
    const int e = tid >> 2, l4 = tid & 3;
    const int eg = e0 + e;
    const int ia1 = a1p[eg], ia2 = a2p[eg];
    if (l4 == 0) atomicAdd(&counts[ia2], 1.0f);
    stage8(&sX[e * 104 + 0 + l4 * 8], atoms + (size_t)ia1 * 32 + l4 * 8);
    stage8(&sX[e * 104 + 32 + l4 * 8], atoms + (size_t)ia2 * 32 + l4 * 8);
    stage8(&sX[e * 104 + 64 + l4 * 8], bonds + (size_t)eg * 32 + l4 * 8);
  }
  __syncthreads();

  const int cl = lane & 15, q = lane >> 4;
  const int et = wv * 16;
  const int eg = e0 + et + cl;      // this lane's edge (output column)

  // ---- GEMM1: h1^T[128][16] = We1^T[128x96] @ x^T[96x16] ----
  bfrag8 xb0, xb1, xb2;
  {
    const unsigned short* xr = &sX[(et + cl) * 104 + q * 8];
    xb0 = *(const bfrag8*)(xr);
    xb1 = *(const bfrag8*)(xr + 32);
    xb2 = *(const bfrag8*)(xr + 64);
  }
#pragma unroll
  for (int rt = 0; rt < 8; ++rt) {
    f32x4 acc = {0.f, 0.f, 0.f, 0.f};
    const unsigned short* wa = &sW[(q * 128 + rt * 16 + cl) * 8];
    acc = mfma16(*(const bfrag8*)(wa), xb0, acc);
    acc = mfma16(*(const bfrag8*)(wa + 4096), xb1, acc);
    acc = mfma16(*(const bfrag8*)(wa + 8192), xb2, acc);
    const int c0 = rt * 16 + q * 4;
    us4 hv;
#pragma unroll
    for (int r = 0; r < 4; ++r) {
      float v = acc[r] + sB1[c0 + r];
      hv[r] = f2bf(fmaxf(v, 0.f));
    }
    *(us4*)&sH1[(et + cl) * 136 + c0] = hv;
  }
  __syncthreads();

  // ---- GEMM2: h2^T[64][16] = We2^T[64x128] @ h1^T ----
  bfrag8 hb[4];
  {
    const unsigned short* hr = &sH1[(et + cl) * 136 + q * 8];
#pragma unroll
    for (int ks = 0; ks < 4; ++ks) hb[ks] = *(const bfrag8*)(hr + ks * 32);
  }
  unsigned short* sH2 = sX;   // reuse (x dead after GEMM1 barrier), stride 72
#pragma unroll
  for (int rt = 0; rt < 4; ++rt) {
    f32x4 acc = {0.f, 0.f, 0.f, 0.f};
#pragma unroll
    for (int ks = 0; ks < 4; ++ks)
      acc = mfma16(*(const bfrag8*)&sW[12288 + ks * 2048 + (q * 64 + rt * 16 + cl) * 8], hb[ks], acc);
    const int c0 = rt * 16 + q * 4;
    us4 hv;
#pragma unroll
    for (int r = 0; r < 4; ++r) {
      float v = acc[r] + sB2[c0 + r];
      hv[r] = f2bf(fmaxf(v, 0.f));
    }
    *(us4*)&sH2[(et + cl) * 72 + c0] = hv;
  }
  __syncthreads();

  // ---- GEMM3: out^T[32][16] = We3^T[32x64] @ h2^T ----
  bfrag8 gb0 = *(const bfrag8*)&sH2[(et + cl) * 72 + q * 8];
  bfrag8 gb1 = *(const bfrag8*)&sH2[(et + cl) * 72 + 32 + q * 8];
  const int a2l = a2p[eg];
  float* nb = new_bonds + (size_t)eg * 32;
  float* sm = sums + (size_t)a2l * 32;
#pragma unroll
  for (int rt = 0; rt < 2; ++rt) {
    f32x4 acc = {0.f, 0.f, 0.f, 0.f};
    acc = mfma16(*(const bfrag8*)&sW[20480 + (q * 32 + rt * 16 + cl) * 8], gb0, acc);
    acc = mfma16(*(const bfrag8*)&sW[20480 + 1024 + (q * 32 + rt * 16 + cl) * 8], gb1, acc);
    const int c0 = rt * 16 + q * 4;
    float4 o;
    o.x = acc[0] + sB3[c0 + 0];
    o.y = acc[1] + sB3[c0 + 1];
    o.z = acc[2] + sB3[c0 + 2];
    o.w = acc[3] + sB3[c0 + 3];
    *(float4*)(nb + c0) = o;
    atomicAdd(sm + c0 + 0, o.x);
    atomicAdd(sm + c0 + 1, o.y);
    atomicAdd(sm + c0 + 2, o.z);
    atomicAdd(sm + c0 + 3, o.w);
  }
}

// ---------------- Node kernel: 64 nodes/block ----------------
__global__ __launch_bounds__(256, 2) void node_kernel(
    const float* __restrict__ atoms,
    const float* __restrict__ bv1, const float* __restrict__ bv2, const float* __restrict__ bv3,
    const unsigned short* __restrict__ wpack,
    const float* __restrict__ counts, float* __restrict__ io /* sums in, new_atoms out */) {
  __shared__ unsigned short sW[18432];          // Wv1p[8192] Wv2p[8192] Wv3p[2048]
  __shared__ float sB1[128], sB2[64], sB3[32];
  __shared__ unsigned short sV[64 * 72];        // v_in [64][64] pad->72; reused as h2
  __shared__ unsigned short sH1[64 * 136];

  const int tid = threadIdx.x;
  const int lane = tid & 63, wv = tid >> 6;
  const int n0 = blockIdx.x * 64;

  {
    const uint4* src = (const uint4*)wpack;
    uint4* dst = (uint4*)sW;
#pragma unroll
    for (int i = 0; i < 9; ++i) dst[tid + i * 256] = src[tid + i * 256];
  }
  if (tid < 128) sB1[tid] = bv1[tid];
  if (tid < 64) sB2[tid] = bv2[tid];
  if (tid < 32) sB3[tid] = bv3[tid];

  // stage v tile: cols [0,32) = mean_bonds, [32,64) = atoms
  {
    const int nl = tid >> 2, l4 = tid & 3;
    const int n = n0 + nl;
    unsigned short* vd = &sV[nl * 72 + l4 * 16];
    if (n < NN) {
      if (l4 < 2) {
        float inv = 1.0f / fmaxf(counts[n], 1.0f);
        const float* sp = io + (size_t)n * 32 + l4 * 16;
        float4 a = *(const float4*)(sp);
        float4 b = *(const float4*)(sp + 4);
        float4 c = *(const float4*)(sp + 8);
        float4 d = *(const float4*)(sp + 12);
        us8 o0, o1;
        o0[0]=f2bf(a.x*inv); o0[1]=f2bf(a.y*inv); o0[2]=f2bf(a.z*inv); o0[3]=f2bf(a.w*inv);
        o0[4]=f2bf(b.x*inv); o0[5]=f2bf(b.y*inv); o0[6]=f2bf(b.z*inv); o0[7]=f2bf(b.w*inv);
        o1[0]=f2bf(c.x*inv); o1[1]=f2bf(c.y*inv); o1[2]=f2bf(c.z*inv); o1[3]=f2bf(c.w*inv);
        o1[4]=f2bf(d.x*inv); o1[5]=f2bf(d.y*inv); o1[6]=f2bf(d.z*inv); o1[7]=f2bf(d.w*inv);
        *(us8*)(vd) = o0;
        *(us8*)(vd + 8) = o1;
      } else {
        stage8(vd, atoms + (size_t)n * 32 + (l4 - 2) * 16);
        stage8(vd + 8, atoms + (size_t)n * 32 + (l4 - 2) * 16 + 8);
      }
    } else {
      us8 z = {0,0,0,0,0,0,0,0};
      *(us8*)(vd) = z;
      *(us8*)(vd + 8) = z;
    }
  }
  __syncthreads();

  const int cl = lane & 15, q = lane >> 4;
  const int nt = wv * 16;
  const int ng = n0 + nt + cl;

  // ---- GEMM1: K=64 ----
  bfrag8 vb0 = *(const bfrag8*)&sV[(nt + cl) * 72 + q * 8];
  bfrag8 vb1 = *(const bfrag8*)&sV[(nt + cl) * 72 + 32 + q * 8];
#pragma unroll
  for (int rt = 0; rt < 8; ++rt) {
    f32x4 acc = {0.f, 0.f, 0.f, 0.f};
    acc = mfma16(*(const bfrag8*)&sW[(q * 128 + rt * 16 + cl) * 8], vb0, acc);
    acc = mfma16(*(const bfrag8*)&sW[4096 + (q * 128 + rt * 16 + cl) * 8], vb1, acc);
    const int c0 = rt * 16 + q * 4;
    us4 hv;
#pragma unroll
    for (int r = 0; r < 4; ++r) {
      float v = acc[r] + sB1[c0 + r];
      hv[r] = f2bf(fmaxf(v, 0.f));
    }
    *(us4*)&sH1[(nt + cl) * 136 + c0] = hv;
  }
  __syncthreads();

  // ---- GEMM2: K=128 ----
  bfrag8 hb[4];
  {
    const unsigned short* hr = &sH1[(nt + cl) * 136 + q * 8];
#pragma unroll
    for (int ks = 0; ks < 4; ++ks) hb[ks] = *(const bfrag8*)(hr + ks * 32);
  }
#pragma unroll
  for (int rt = 0; rt < 4; ++rt) {
    f32x4 acc = {0.f, 0.f, 0.f, 0.f};
#pragma unroll
    for (int ks = 0; ks < 4; ++ks)
      acc = mfma16(*(const bfrag8*)&sW[8192 + ks * 2048 + (q * 64 + rt * 16 + cl) * 8], hb[ks], acc);
    const int c0 = rt * 16 + q * 4;
    us4 hv;
#pragma unroll
    for (int r = 0; r < 4; ++r) {
      float v = acc[r] + sB2[c0 + r];
      hv[r] = f2bf(fmaxf(v, 0.f));
    }
    *(us4*)&sV[(nt + cl) * 72 + c0] = hv;   // reuse sV as h2
  }
  __syncthreads();

  // ---- GEMM3: K=64, no relu ----
  bfrag8 gb0 = *(const bfrag8*)&sV[(nt + cl) * 72 + q * 8];
  bfrag8 gb1 = *(const bfrag8*)&sV[(nt + cl) * 72 + 32 + q * 8];
  if (ng < NN) {
    float* outp = io + (size_t)ng * 32;
#pragma unroll
    for (int rt = 0; rt < 2; ++rt) {
      f32x4 acc = {0.f, 0.f, 0.f, 0.f};
      acc = mfma16(*(const bfrag8*)&sW[16384 + (q * 32 + rt * 16 + cl) * 8], gb0, acc);
      acc = mfma16(*(const bfrag8*)&sW[16384 + 1024 + (q * 32 + rt * 16 + cl) * 8], gb1, acc);
      const int c0 = rt * 16 + q * 4;
      float4 o;
      o.x = acc[0] + sB3[c0 + 0];
      o.y = acc[1] + sB3[c0 + 1];
      o.z = acc[2] + sB3[c0 + 2];
      o.w = acc[3] + sB3[c0 + 3];
      *(float4*)(outp + c0) = o;
    }
  } else {
    // still execute MFMAs for uniformity? Not needed; guarded out.
  }
}

extern "C" void kernel_launch(void* const* d_in, const int* in_sizes, int n_in,
                              void* d_out, int out_size, void* d_ws, size_t ws_size,
                              hipStream_t stream) {
  const float* bonds = (const float*)d_in[0];
  const int* a1 = (const int*)d_in[1];
  const int* a2 = (const int*)d_in[2];
  const float* atoms = (const float*)d_in[3];
  const float* We1 = (const float*)d_in[4];
  const float* be1 = (const float*)d_in[5];
  const float* We2 = (const float*)d_in[6];
  const float* be2 = (const float*)d_in[7];
  const float* We3 = (const float*)d_in[8];
  const float* be3 = (const float*)d_in[9];
  const float* Wv1 = (const float*)d_in[10];
  const float* bv1 = (const float*)d_in[11];
  const float* Wv2 = (const float*)d_in[12];
  const float* bv2 = (const float*)d_in[13];
  const float* Wv3 = (const float*)d_in[14];
  const float* bv3 = (const float*)d_in[15];

  float* out = (float*)d_out;
  float* new_atoms = out;                       // [NN*32], doubles as scatter-sum accumulator
  float* new_bonds = out + (size_t)NN * 32;     // [NE*32]
  float* counts = (float*)d_ws;                 // [NN] f32
  unsigned short* wp = (unsigned short*)((char*)d_ws + 400000);  // packed bf16 weights

  hipMemsetAsync(counts, 0, (size_t)NN * 4, stream);
  hipMemsetAsync(new_atoms, 0, (size_t)NN * 32 * 4, stream);

  pack_w<<<48, 256, 0, stream>>>(We1, wp + 0, 96, 128);
  pack_w<<<32, 256, 0, stream>>>(We2, wp + 12288, 128, 64);
  pack_w<<<8, 256, 0, stream>>>(We3, wp + 20480, 64, 32);
  pack_w<<<32, 256, 0, stream>>>(Wv1, wp + 22528, 64, 128);
  pack_w<<<32, 256, 0, stream>>>(Wv2, wp + 30720, 128, 64);
  pack_w<<<8, 256, 0, stream>>>(Wv3, wp + 38912, 64, 32);

  edge_kernel<<<NE / 64, 256, 0, stream>>>(bonds, a1, a2, atoms, be1, be2, be3, wp,
                                           new_bonds, new_atoms, counts);
  node_kernel<<<(NN + 63) / 64, 256, 0, stream>>>(atoms, bv1, bv2, bv3, wp + 22528,
                                                  counts, new_atoms);
}

// Round 2
// 790.882 us; speedup vs baseline: 1.0271x; 1.0271x over previous
//
#include <hip/hip_runtime.h>
#include <hip/hip_bf16.h>

#define NN 100000
#define NE 1600000

typedef __attribute__((ext_vector_type(8))) short bfrag8;   // 8 bf16 (4 VGPRs) MFMA operand
typedef __attribute__((ext_vector_type(4))) float f32x4;    // MFMA accumulator
typedef __attribute__((ext_vector_type(4))) unsigned short us4;
typedef __attribute__((ext_vector_type(8))) unsigned short us8;

__device__ __forceinline__ unsigned short f2bf(float f) {
  unsigned int u = __float_as_uint(f);
  u += 0x7fffu + ((u >> 16) & 1u);   // RNE
  return (unsigned short)(u >> 16);
}

__device__ __forceinline__ f32x4 mfma16(bfrag8 a, bfrag8 b, f32x4 c) {
  return __builtin_amdgcn_mfma_f32_16x16x32_bf16(a, b, c, 0, 0, 0);
}

__device__ __forceinline__ bfrag8 ld_cvt8(const float* p) {
  float4 a = *(const float4*)p;
  float4 b = *(const float4*)(p + 4);
  bfrag8 r;
  r[0] = (short)f2bf(a.x); r[1] = (short)f2bf(a.y);
  r[2] = (short)f2bf(a.z); r[3] = (short)f2bf(a.w);
  r[4] = (short)f2bf(b.x); r[5] = (short)f2bf(b.y);
  r[6] = (short)f2bf(b.z); r[7] = (short)f2bf(b.w);
  return r;
}

__device__ __forceinline__ void gload_lds16(const void* g, void* l) {
  __builtin_amdgcn_global_load_lds(
      (const __attribute__((address_space(1))) unsigned int*)g,
      (__attribute__((address_space(3))) unsigned int*)l, 16, 0, 0);
}

__device__ __forceinline__ void stage8(unsigned short* dst, const float* src) {
  float4 a = *(const float4*)src;
  float4 b = *(const float4*)(src + 4);
  us8 o;
  o[0] = f2bf(a.x); o[1] = f2bf(a.y); o[2] = f2bf(a.z); o[3] = f2bf(a.w);
  o[4] = f2bf(b.x); o[5] = f2bf(b.y); o[6] = f2bf(b.z); o[7] = f2bf(b.w);
  *(us8*)dst = o;
}

// Pack W[K][N] f32 row-major -> Wp[g][c][j] bf16 with k = g*8+j (fragment-linear)
__global__ void pack_w(const float* __restrict__ src, unsigned short* __restrict__ dst,
                       int K, int N) {
  int i = blockIdx.x * 256 + threadIdx.x;
  if (i >= K * N) return;
  int j = i & 7;
  int gc = i >> 3;        // g*N + c
  int c = gc % N;
  int g = gc / N;
  dst[i] = f2bf(src[(g * 8 + j) * N + c]);
}

// ---------------- Edge kernel: 128 edges/block, 4 waves, wave owns 32 edges (2 col-tiles) ----
__global__ __launch_bounds__(256, 2) void edge_kernel(
    const float* __restrict__ bonds, const int* __restrict__ a1p, const int* __restrict__ a2p,
    const float* __restrict__ atoms,
    const float* __restrict__ be1, const float* __restrict__ be2, const float* __restrict__ be3,
    const unsigned short* __restrict__ wpack,
    float* __restrict__ new_bonds, float* __restrict__ sums, float* __restrict__ counts) {
  __shared__ unsigned short sW[22528];          // We1p[12288] We2p[8192] We3p[2048] = 45056 B
  __shared__ float sB1[128], sB2[64], sB3[32];
  __shared__ unsigned short sH1[128 * 136];     // h1 [128][128] pad->136 (34816 B); aliased as h2 [128][72]

  const int tid = threadIdx.x;
  const int lane = tid & 63, wv = tid >> 6;
  const int cl = lane & 15, q = lane >> 4;
  const int e0 = blockIdx.x * 128;

  // ---- async weight staging: 44 chunks x 1024 B, wave-uniform LDS dest + lane*16 global src
  {
    const char* src = (const char*)wpack;
    char* dst = (char*)sW;
#pragma unroll
    for (int i = 0; i < 11; ++i) {
      const int c = i * 4 + wv;
      gload_lds16(src + c * 1024 + lane * 16, dst + c * 1024);
    }
  }
  if (tid < 128) sB1[tid] = be1[tid];
  else if (tid < 192) sB2[tid - 128] = be2[tid - 128];
  else if (tid < 224) sB3[tid - 192] = be3[tid - 192];

  // ---- B-fragments direct from global (overlaps the weight DMA)
  int i2[2];
  bfrag8 xb[2][3];
#pragma unroll
  for (int t = 0; t < 2; ++t) {
    const int e = e0 + wv * 32 + t * 16 + cl;
    const int ia1 = a1p[e];
    const int ia2 = a2p[e];
    i2[t] = ia2;
    xb[t][0] = ld_cvt8(atoms + (size_t)ia1 * 32 + q * 8);
    xb[t][1] = ld_cvt8(atoms + (size_t)ia2 * 32 + q * 8);
    xb[t][2] = ld_cvt8(bonds + (size_t)e * 32 + q * 8);
    if (q == 0) unsafeAtomicAdd(&counts[ia2], 1.0f);
  }
  __syncthreads();   // weights + biases staged

  // ---- GEMM1: h1^T[128][16x2] = We1^T[128x96] @ x^T ----
#pragma unroll
  for (int rt = 0; rt < 8; ++rt) {
    const unsigned short* wa = &sW[(q * 128 + rt * 16 + cl) * 8];
    bfrag8 w0 = *(const bfrag8*)(wa);
    bfrag8 w1 = *(const bfrag8*)(wa + 4096);
    bfrag8 w2 = *(const bfrag8*)(wa + 8192);
    f32x4 acc[2];
    acc[0] = (f32x4){0.f, 0.f, 0.f, 0.f};
    acc[1] = (f32x4){0.f, 0.f, 0.f, 0.f};
#pragma unroll
    for (int t = 0; t < 2; ++t) {
      acc[t] = mfma16(w0, xb[t][0], acc[t]);
      acc[t] = mfma16(w1, xb[t][1], acc[t]);
      acc[t] = mfma16(w2, xb[t][2], acc[t]);
    }
    const int c0 = rt * 16 + q * 4;
#pragma unroll
    for (int t = 0; t < 2; ++t) {
      us4 hv;
#pragma unroll
      for (int r = 0; r < 4; ++r) hv[r] = f2bf(fmaxf(acc[t][r] + sB1[c0 + r], 0.f));
      *(us4*)&sH1[(wv * 32 + t * 16 + cl) * 136 + c0] = hv;
    }
  }
  __syncthreads();   // h1 complete

  // ---- GEMM2: h2^T[64][16x2] = We2^T[64x128] @ h1^T ----
  bfrag8 hb[4][2];
#pragma unroll
  for (int t = 0; t < 2; ++t) {
    const unsigned short* hr = &sH1[(wv * 32 + t * 16 + cl) * 136 + q * 8];
#pragma unroll
    for (int ks = 0; ks < 4; ++ks) hb[ks][t] = *(const bfrag8*)(hr + ks * 32);
  }
  __syncthreads();   // all h1 reads done -> safe to overwrite region as h2

  unsigned short* sH2 = sH1;   // stride 72
#pragma unroll
  for (int rt = 0; rt < 4; ++rt) {
    f32x4 acc[2];
    acc[0] = (f32x4){0.f, 0.f, 0.f, 0.f};
    acc[1] = (f32x4){0.f, 0.f, 0.f, 0.f};
#pragma unroll
    for (int ks = 0; ks < 4; ++ks) {
      bfrag8 w = *(const bfrag8*)&sW[12288 + ks * 2048 + (q * 64 + rt * 16 + cl) * 8];
#pragma unroll
      for (int t = 0; t < 2; ++t) acc[t] = mfma16(w, hb[ks][t], acc[t]);
    }
    const int c0 = rt * 16 + q * 4;
#pragma unroll
    for (int t = 0; t < 2; ++t) {
      us4 hv;
#pragma unroll
      for (int r = 0; r < 4; ++r) hv[r] = f2bf(fmaxf(acc[t][r] + sB2[c0 + r], 0.f));
      *(us4*)&sH2[(wv * 32 + t * 16 + cl) * 72 + c0] = hv;
    }
  }
  __syncthreads();   // h2 complete

  // ---- GEMM3: out^T[32][16x2] = We3^T[32x64] @ h2^T ----
  bfrag8 gb0[2], gb1[2];
#pragma unroll
  for (int t = 0; t < 2; ++t) {
    const unsigned short* hr = &sH2[(wv * 32 + t * 16 + cl) * 72 + q * 8];
    gb0[t] = *(const bfrag8*)(hr);
    gb1[t] = *(const bfrag8*)(hr + 32);
  }
#pragma unroll
  for (int rt = 0; rt < 2; ++rt) {
    bfrag8 w0 = *(const bfrag8*)&sW[20480 + (q * 32 + rt * 16 + cl) * 8];
    bfrag8 w1 = *(const bfrag8*)&sW[20480 + 1024 + (q * 32 + rt * 16 + cl) * 8];
    const int c0 = rt * 16 + q * 4;
#pragma unroll
    for (int t = 0; t < 2; ++t) {
      f32x4 acc = {0.f, 0.f, 0.f, 0.f};
      acc = mfma16(w0, gb0[t], acc);
      acc = mfma16(w1, gb1[t], acc);
      const int e = e0 + wv * 32 + t * 16 + cl;
      float4 o;
      o.x = acc[0] + sB3[c0 + 0];
      o.y = acc[1] + sB3[c0 + 1];
      o.z = acc[2] + sB3[c0 + 2];
      o.w = acc[3] + sB3[c0 + 3];
      *(float4*)(new_bonds + (size_t)e * 32 + c0) = o;
      float* sm = sums + (size_t)i2[t] * 32 + c0;
      unsafeAtomicAdd(sm + 0, o.x);
      unsafeAtomicAdd(sm + 1, o.y);
      unsafeAtomicAdd(sm + 2, o.z);
      unsafeAtomicAdd(sm + 3, o.w);
    }
  }
}

// ---------------- Node kernel: 64 nodes/block ----------------
__global__ __launch_bounds__(256, 2) void node_kernel(
    const float* __restrict__ atoms,
    const float* __restrict__ bv1, const float* __restrict__ bv2, const float* __restrict__ bv3,
    const unsigned short* __restrict__ wpack,
    const float* __restrict__ counts, float* __restrict__ io /* sums in, new_atoms out */) {
  __shared__ unsigned short sW[18432];          // Wv1p[8192] Wv2p[8192] Wv3p[2048]
  __shared__ float sB1[128], sB2[64], sB3[32];
  __shared__ unsigned short sV[64 * 72];        // v_in [64][64] pad->72; reused as h2
  __shared__ unsigned short sH1[64 * 136];

  const int tid = threadIdx.x;
  const int lane = tid & 63, wv = tid >> 6;
  const int n0 = blockIdx.x * 64;

  {
    const uint4* src = (const uint4*)wpack;
    uint4* dst = (uint4*)sW;
#pragma unroll
    for (int i = 0; i < 9; ++i) dst[tid + i * 256] = src[tid + i * 256];
  }
  if (tid < 128) sB1[tid] = bv1[tid];
  if (tid < 64) sB2[tid] = bv2[tid];
  if (tid < 32) sB3[tid] = bv3[tid];

  // stage v tile: cols [0,32) = mean_bonds, [32,64) = atoms
  {
    const int nl = tid >> 2, l4 = tid & 3;
    const int n = n0 + nl;
    unsigned short* vd = &sV[nl * 72 + l4 * 16];
    if (n < NN) {
      if (l4 < 2) {
        float inv = 1.0f / fmaxf(counts[n], 1.0f);
        const float* sp = io + (size_t)n * 32 + l4 * 16;
        float4 a = *(const float4*)(sp);
        float4 b = *(const float4*)(sp + 4);
        float4 c = *(const float4*)(sp + 8);
        float4 d = *(const float4*)(sp + 12);
        us8 o0, o1;
        o0[0]=f2bf(a.x*inv); o0[1]=f2bf(a.y*inv); o0[2]=f2bf(a.z*inv); o0[3]=f2bf(a.w*inv);
        o0[4]=f2bf(b.x*inv); o0[5]=f2bf(b.y*inv); o0[6]=f2bf(b.z*inv); o0[7]=f2bf(b.w*inv);
        o1[0]=f2bf(c.x*inv); o1[1]=f2bf(c.y*inv); o1[2]=f2bf(c.z*inv); o1[3]=f2bf(c.w*inv);
        o1[4]=f2bf(d.x*inv); o1[5]=f2bf(d.y*inv); o1[6]=f2bf(d.z*inv); o1[7]=f2bf(d.w*inv);
        *(us8*)(vd) = o0;
        *(us8*)(vd + 8) = o1;
      } else {
        stage8(vd, atoms + (size_t)n * 32 + (l4 - 2) * 16);
        stage8(vd + 8, atoms + (size_t)n * 32 + (l4 - 2) * 16 + 8);
      }
    } else {
      us8 z = {0,0,0,0,0,0,0,0};
      *(us8*)(vd) = z;
      *(us8*)(vd + 8) = z;
    }
  }
  __syncthreads();

  const int cl = lane & 15, q = lane >> 4;
  const int nt = wv * 16;
  const int ng = n0 + nt + cl;

  // ---- GEMM1: K=64 ----
  bfrag8 vb0 = *(const bfrag8*)&sV[(nt + cl) * 72 + q * 8];
  bfrag8 vb1 = *(const bfrag8*)&sV[(nt + cl) * 72 + 32 + q * 8];
#pragma unroll
  for (int rt = 0; rt < 8; ++rt) {
    f32x4 acc = {0.f, 0.f, 0.f, 0.f};
    acc = mfma16(*(const bfrag8*)&sW[(q * 128 + rt * 16 + cl) * 8], vb0, acc);
    acc = mfma16(*(const bfrag8*)&sW[4096 + (q * 128 + rt * 16 + cl) * 8], vb1, acc);
    const int c0 = rt * 16 + q * 4;
    us4 hv;
#pragma unroll
    for (int r = 0; r < 4; ++r) {
      float v = acc[r] + sB1[c0 + r];
      hv[r] = f2bf(fmaxf(v, 0.f));
    }
    *(us4*)&sH1[(nt + cl) * 136 + c0] = hv;
  }
  __syncthreads();

  // ---- GEMM2: K=128 ----
  bfrag8 hb[4];
  {
    const unsigned short* hr = &sH1[(nt + cl) * 136 + q * 8];
#pragma unroll
    for (int ks = 0; ks < 4; ++ks) hb[ks] = *(const bfrag8*)(hr + ks * 32);
  }
#pragma unroll
  for (int rt = 0; rt < 4; ++rt) {
    f32x4 acc = {0.f, 0.f, 0.f, 0.f};
#pragma unroll
    for (int ks = 0; ks < 4; ++ks)
      acc = mfma16(*(const bfrag8*)&sW[8192 + ks * 2048 + (q * 64 + rt * 16 + cl) * 8], hb[ks], acc);
    const int c0 = rt * 16 + q * 4;
    us4 hv;
#pragma unroll
    for (int r = 0; r < 4; ++r) {
      float v = acc[r] + sB2[c0 + r];
      hv[r] = f2bf(fmaxf(v, 0.f));
    }
    *(us4*)&sV[(nt + cl) * 72 + c0] = hv;   // reuse sV as h2
  }
  __syncthreads();

  // ---- GEMM3: K=64, no relu ----
  bfrag8 gb0 = *(const bfrag8*)&sV[(nt + cl) * 72 + q * 8];
  bfrag8 gb1 = *(const bfrag8*)&sV[(nt + cl) * 72 + 32 + q * 8];
  if (ng < NN) {
    float* outp = io + (size_t)ng * 32;
#pragma unroll
    for (int rt = 0; rt < 2; ++rt) {
      f32x4 acc = {0.f, 0.f, 0.f, 0.f};
      acc = mfma16(*(const bfrag8*)&sW[16384 + (q * 32 + rt * 16 + cl) * 8], gb0, acc);
      acc = mfma16(*(const bfrag8*)&sW[16384 + 1024 + (q * 32 + rt * 16 + cl) * 8], gb1, acc);
      const int c0 = rt * 16 + q * 4;
      float4 o;
      o.x = acc[0] + sB3[c0 + 0];
      o.y = acc[1] + sB3[c0 + 1];
      o.z = acc[2] + sB3[c0 + 2];
      o.w = acc[3] + sB3[c0 + 3];
      *(float4*)(outp + c0) = o;
    }
  }
}

extern "C" void kernel_launch(void* const* d_in, const int* in_sizes, int n_in,
                              void* d_out, int out_size, void* d_ws, size_t ws_size,
                              hipStream_t stream) {
  const float* bonds = (const float*)d_in[0];
  const int* a1 = (const int*)d_in[1];
  const int* a2 = (const int*)d_in[2];
  const float* atoms = (const float*)d_in[3];
  const float* We1 = (const float*)d_in[4];
  const float* be1 = (const float*)d_in[5];
  const float* We2 = (const float*)d_in[6];
  const float* be2 = (const float*)d_in[7];
  const float* We3 = (const float*)d_in[8];
  const float* be3 = (const float*)d_in[9];
  const float* Wv1 = (const float*)d_in[10];
  const float* bv1 = (const float*)d_in[11];
  const float* Wv2 = (const float*)d_in[12];
  const float* bv2 = (const float*)d_in[13];
  const float* Wv3 = (const float*)d_in[14];
  const float* bv3 = (const float*)d_in[15];

  float* out = (float*)d_out;
  float* new_atoms = out;                       // [NN*32], doubles as scatter-sum accumulator
  float* new_bonds = out + (size_t)NN * 32;     // [NE*32]
  float* counts = (float*)d_ws;                 // [NN] f32
  unsigned short* wp = (unsigned short*)((char*)d_ws + 400000);  // packed bf16 weights

  hipMemsetAsync(counts, 0, (size_t)NN * 4, stream);
  hipMemsetAsync(new_atoms, 0, (size_t)NN * 32 * 4, stream);

  pack_w<<<48, 256, 0, stream>>>(We1, wp + 0, 96, 128);
  pack_w<<<32, 256, 0, stream>>>(We2, wp + 12288, 128, 64);
  pack_w<<<8, 256, 0, stream>>>(We3, wp + 20480, 64, 32);
  pack_w<<<32, 256, 0, stream>>>(Wv1, wp + 22528, 64, 128);
  pack_w<<<32, 256, 0, stream>>>(Wv2, wp + 30720, 128, 64);
  pack_w<<<8, 256, 0, stream>>>(Wv3, wp + 38912, 64, 32);

  edge_kernel<<<NE / 128, 256, 0, stream>>>(bonds, a1, a2, atoms, be1, be2, be3, wp,
                                            new_bonds, new_atoms, counts);
  node_kernel<<<(NN + 63) / 64, 256, 0, stream>>>(atoms, bv1, bv2, bv3, wp + 22528,
                                                  counts, new_atoms);
}

// Round 3
// 456.357 us; speedup vs baseline: 1.7801x; 1.7330x over previous
//
#include <hip/hip_runtime.h>
#include <hip/hip_bf16.h>

#define NN 100000
#define NE 1600000
#define NB_SCAN 391   // ceil(NN/256)

typedef __attribute__((ext_vector_type(8))) short bfrag8;   // 8 bf16 (4 VGPRs) MFMA operand
typedef __attribute__((ext_vector_type(4))) float f32x4;    // MFMA accumulator
typedef __attribute__((ext_vector_type(4))) unsigned short us4;
typedef __attribute__((ext_vector_type(8))) unsigned short us8;

__device__ __forceinline__ unsigned short f2bf(float f) {
  unsigned int u = __float_as_uint(f);
  u += 0x7fffu + ((u >> 16) & 1u);   // RNE
  return (unsigned short)(u >> 16);
}

__device__ __forceinline__ f32x4 mfma16(bfrag8 a, bfrag8 b, f32x4 c) {
  return __builtin_amdgcn_mfma_f32_16x16x32_bf16(a, b, c, 0, 0, 0);
}

__device__ __forceinline__ bfrag8 ld_cvt8(const float* p) {
  float4 a = *(const float4*)p;
  float4 b = *(const float4*)(p + 4);
  bfrag8 r;
  r[0] = (short)f2bf(a.x); r[1] = (short)f2bf(a.y);
  r[2] = (short)f2bf(a.z); r[3] = (short)f2bf(a.w);
  r[4] = (short)f2bf(b.x); r[5] = (short)f2bf(b.y);
  r[6] = (short)f2bf(b.z); r[7] = (short)f2bf(b.w);
  return r;
}

__device__ __forceinline__ void gload_lds16(const void* g, void* l) {
  __builtin_amdgcn_global_load_lds(
      (const __attribute__((address_space(1))) unsigned int*)g,
      (__attribute__((address_space(3))) unsigned int*)l, 16, 0, 0);
}

__device__ __forceinline__ void stage8(unsigned short* dst, const float* src) {
  float4 a = *(const float4*)src;
  float4 b = *(const float4*)(src + 4);
  us8 o;
  o[0] = f2bf(a.x); o[1] = f2bf(a.y); o[2] = f2bf(a.z); o[3] = f2bf(a.w);
  o[4] = f2bf(b.x); o[5] = f2bf(b.y); o[6] = f2bf(b.z); o[7] = f2bf(b.w);
  *(us8*)dst = o;
}

// Pack W[K][N] f32 row-major -> Wp[g][c][j] bf16 with k = g*8+j (fragment-linear)
__global__ void pack_w(const float* __restrict__ src, unsigned short* __restrict__ dst,
                       int K, int N) {
  int i = blockIdx.x * 256 + threadIdx.x;
  if (i >= K * N) return;
  int j = i & 7;
  int gc = i >> 3;        // g*N + c
  int c = gc % N;
  int g = gc / N;
  dst[i] = f2bf(src[(g * 8 + j) * N + c]);
}

// ---------------- CSR construction ----------------
__global__ void count_k(const int* __restrict__ a2, int* __restrict__ cnt) {
  int e = blockIdx.x * 256 + threadIdx.x;
  if (e < NE) atomicAdd(&cnt[a2[e]], 1);
}

__global__ void scan_blocks(const int* __restrict__ cnt, int* __restrict__ off,
                            int* __restrict__ bsum) {
  __shared__ int s[256];
  const int t = threadIdx.x;
  const int idx = blockIdx.x * 256 + t;
  int v = (idx < NN) ? cnt[idx] : 0;
  s[t] = v;
  __syncthreads();
  for (int d = 1; d < 256; d <<= 1) {
    int x = (t >= d) ? s[t - d] : 0;
    __syncthreads();
    s[t] += x;
    __syncthreads();
  }
  if (idx < NN) off[idx] = s[t] - v;          // exclusive within block
  if (t == 255) bsum[blockIdx.x] = s[255];
}

__global__ void scan_bsum(int* __restrict__ bsum) {   // single block of 512
  __shared__ int s[512];
  const int t = threadIdx.x;
  int v = (t < NB_SCAN) ? bsum[t] : 0;
  s[t] = v;
  __syncthreads();
  for (int d = 1; d < 512; d <<= 1) {
    int x = (t >= d) ? s[t - d] : 0;
    __syncthreads();
    s[t] += x;
    __syncthreads();
  }
  if (t < NB_SCAN) bsum[t] = s[t] - v;        // exclusive block bases
}

__global__ void scan_finalize(int* __restrict__ off, const int* __restrict__ bsum,
                              int* __restrict__ cursor) {
  int idx = blockIdx.x * 256 + threadIdx.x;
  if (idx < NN) {
    int o = off[idx] + bsum[blockIdx.x];
    off[idx] = o;
    cursor[idx] = o;
  }
  if (idx == 0) off[NN] = NE;
}

__global__ void fill_csr(const int* __restrict__ a2, int* __restrict__ cursor,
                         int* __restrict__ csr) {
  int e = blockIdx.x * 256 + threadIdx.x;
  if (e < NE) {
    int p = atomicAdd(&cursor[a2[e]], 1);
    csr[p] = e;
  }
}

// ---------------- Edge kernel: 128 edges/block, 4 waves, wave owns 32 edges (2 col-tiles) ----
__global__ __launch_bounds__(256, 2) void edge_kernel(
    const float* __restrict__ bonds, const int* __restrict__ a1p, const int* __restrict__ a2p,
    const float* __restrict__ atoms,
    const float* __restrict__ be1, const float* __restrict__ be2, const float* __restrict__ be3,
    const unsigned short* __restrict__ wpack,
    float* __restrict__ new_bonds) {
  __shared__ unsigned short sW[22528];          // We1p[12288] We2p[8192] We3p[2048] = 45056 B
  __shared__ float sB1[128], sB2[64], sB3[32];
  __shared__ unsigned short sH1[128 * 136];     // h1 [128][128] pad->136; aliased as h2 [128][72]

  const int tid = threadIdx.x;
  const int lane = tid & 63, wv = tid >> 6;
  const int cl = lane & 15, q = lane >> 4;
  const int e0 = blockIdx.x * 128;

  // ---- async weight staging: 44 chunks x 1024 B
  {
    const char* src = (const char*)wpack;
    char* dst = (char*)sW;
#pragma unroll
    for (int i = 0; i < 11; ++i) {
      const int c = i * 4 + wv;
      gload_lds16(src + c * 1024 + lane * 16, dst + c * 1024);
    }
  }
  if (tid < 128) sB1[tid] = be1[tid];
  else if (tid < 192) sB2[tid - 128] = be2[tid - 128];
  else if (tid < 224) sB3[tid - 192] = be3[tid - 192];

  // ---- B-fragments direct from global (overlaps the weight DMA)
  bfrag8 xb[2][3];
#pragma unroll
  for (int t = 0; t < 2; ++t) {
    const int e = e0 + wv * 32 + t * 16 + cl;
    const int ia1 = a1p[e];
    const int ia2 = a2p[e];
    xb[t][0] = ld_cvt8(atoms + (size_t)ia1 * 32 + q * 8);
    xb[t][1] = ld_cvt8(atoms + (size_t)ia2 * 32 + q * 8);
    xb[t][2] = ld_cvt8(bonds + (size_t)e * 32 + q * 8);
  }
  __syncthreads();   // weights + biases staged

  // ---- GEMM1: h1^T[128][16x2] = We1^T[128x96] @ x^T ----
#pragma unroll
  for (int rt = 0; rt < 8; ++rt) {
    const unsigned short* wa = &sW[(q * 128 + rt * 16 + cl) * 8];
    bfrag8 w0 = *(const bfrag8*)(wa);
    bfrag8 w1 = *(const bfrag8*)(wa + 4096);
    bfrag8 w2 = *(const bfrag8*)(wa + 8192);
    f32x4 acc[2];
    acc[0] = (f32x4){0.f, 0.f, 0.f, 0.f};
    acc[1] = (f32x4){0.f, 0.f, 0.f, 0.f};
#pragma unroll
    for (int t = 0; t < 2; ++t) {
      acc[t] = mfma16(w0, xb[t][0], acc[t]);
      acc[t] = mfma16(w1, xb[t][1], acc[t]);
      acc[t] = mfma16(w2, xb[t][2], acc[t]);
    }
    const int c0 = rt * 16 + q * 4;
#pragma unroll
    for (int t = 0; t < 2; ++t) {
      us4 hv;
#pragma unroll
      for (int r = 0; r < 4; ++r) hv[r] = f2bf(fmaxf(acc[t][r] + sB1[c0 + r], 0.f));
      *(us4*)&sH1[(wv * 32 + t * 16 + cl) * 136 + c0] = hv;
    }
  }
  __syncthreads();   // h1 complete

  // ---- GEMM2: h2^T[64][16x2] = We2^T[64x128] @ h1^T ----
  bfrag8 hb[4][2];
#pragma unroll
  for (int t = 0; t < 2; ++t) {
    const unsigned short* hr = &sH1[(wv * 32 + t * 16 + cl) * 136 + q * 8];
#pragma unroll
    for (int ks = 0; ks < 4; ++ks) hb[ks][t] = *(const bfrag8*)(hr + ks * 32);
  }
  __syncthreads();   // all h1 reads done -> safe to overwrite region as h2

  unsigned short* sH2 = sH1;   // stride 72
#pragma unroll
  for (int rt = 0; rt < 4; ++rt) {
    f32x4 acc[2];
    acc[0] = (f32x4){0.f, 0.f, 0.f, 0.f};
    acc[1] = (f32x4){0.f, 0.f, 0.f, 0.f};
#pragma unroll
    for (int ks = 0; ks < 4; ++ks) {
      bfrag8 w = *(const bfrag8*)&sW[12288 + ks * 2048 + (q * 64 + rt * 16 + cl) * 8];
#pragma unroll
      for (int t = 0; t < 2; ++t) acc[t] = mfma16(w, hb[ks][t], acc[t]);
    }
    const int c0 = rt * 16 + q * 4;
#pragma unroll
    for (int t = 0; t < 2; ++t) {
      us4 hv;
#pragma unroll
      for (int r = 0; r < 4; ++r) hv[r] = f2bf(fmaxf(acc[t][r] + sB2[c0 + r], 0.f));
      *(us4*)&sH2[(wv * 32 + t * 16 + cl) * 72 + c0] = hv;
    }
  }
  __syncthreads();   // h2 complete

  // ---- GEMM3: out^T[32][16x2] = We3^T[32x64] @ h2^T ----
  bfrag8 gb0[2], gb1[2];
#pragma unroll
  for (int t = 0; t < 2; ++t) {
    const unsigned short* hr = &sH2[(wv * 32 + t * 16 + cl) * 72 + q * 8];
    gb0[t] = *(const bfrag8*)(hr);
    gb1[t] = *(const bfrag8*)(hr + 32);
  }
#pragma unroll
  for (int rt = 0; rt < 2; ++rt) {
    bfrag8 w0 = *(const bfrag8*)&sW[20480 + (q * 32 + rt * 16 + cl) * 8];
    bfrag8 w1 = *(const bfrag8*)&sW[20480 + 1024 + (q * 32 + rt * 16 + cl) * 8];
    const int c0 = rt * 16 + q * 4;
#pragma unroll
    for (int t = 0; t < 2; ++t) {
      f32x4 acc = {0.f, 0.f, 0.f, 0.f};
      acc = mfma16(w0, gb0[t], acc);
      acc = mfma16(w1, gb1[t], acc);
      const int e = e0 + wv * 32 + t * 16 + cl;
      float4 o;
      o.x = acc[0] + sB3[c0 + 0];
      o.y = acc[1] + sB3[c0 + 1];
      o.z = acc[2] + sB3[c0 + 2];
      o.w = acc[3] + sB3[c0 + 3];
      *(float4*)(new_bonds + (size_t)e * 32 + c0) = o;
    }
  }
}

// ---------------- Node kernel: 64 nodes/block, CSR gather-mean + MLP ----------------
__global__ __launch_bounds__(256, 2) void node_kernel(
    const float* __restrict__ atoms,
    const float* __restrict__ bv1, const float* __restrict__ bv2, const float* __restrict__ bv3,
    const unsigned short* __restrict__ wpack,
    const int* __restrict__ off, const int* __restrict__ csr,
    const float* __restrict__ new_bonds, float* __restrict__ new_atoms) {
  __shared__ unsigned short sW[18432];          // Wv1p[8192] Wv2p[8192] Wv3p[2048]
  __shared__ float sB1[128], sB2[64], sB3[32];
  __shared__ unsigned short sV[64 * 72];        // v_in [64][64] pad->72; reused as h2
  __shared__ unsigned short sH1[64 * 136];

  const int tid = threadIdx.x;
  const int lane = tid & 63, wv = tid >> 6;
  const int n0 = blockIdx.x * 64;

  {
    const uint4* src = (const uint4*)wpack;
    uint4* dst = (uint4*)sW;
#pragma unroll
    for (int i = 0; i < 9; ++i) dst[tid + i * 256] = src[tid + i * 256];
  }
  if (tid < 128) sB1[tid] = bv1[tid];
  if (tid < 64) sB2[tid] = bv2[tid];
  if (tid < 32) sB3[tid] = bv3[tid];

  // stage v tile: cols [0,32) = mean_bonds (CSR gather), [32,64) = atoms
  {
    const int nl = tid >> 2, l4 = tid & 3;    // 4 threads per node, 8 cols each
    const int n = n0 + nl;
    unsigned short* vd = &sV[nl * 72 + l4 * 8];
    if (n < NN) {
      const int o0 = off[n], o1 = off[n + 1];
      float s0x = 0.f, s0y = 0.f, s0z = 0.f, s0w = 0.f;
      float s1x = 0.f, s1y = 0.f, s1z = 0.f, s1w = 0.f;
      int i = o0;
      if (i < o1) {
        int e = csr[i];
        while (++i < o1) {
          int en = csr[i];                    // prefetch next id (1-deep pipeline)
          const float4* r = (const float4*)(new_bonds + (size_t)e * 32 + l4 * 8);
          float4 a = r[0], b = r[1];
          s0x += a.x; s0y += a.y; s0z += a.z; s0w += a.w;
          s1x += b.x; s1y += b.y; s1z += b.z; s1w += b.w;
          e = en;
        }
        const float4* r = (const float4*)(new_bonds + (size_t)e * 32 + l4 * 8);
        float4 a = r[0], b = r[1];
        s0x += a.x; s0y += a.y; s0z += a.z; s0w += a.w;
        s1x += b.x; s1y += b.y; s1z += b.z; s1w += b.w;
      }
      const float inv = 1.0f / fmaxf((float)(o1 - o0), 1.0f);
      us8 m;
      m[0] = f2bf(s0x * inv); m[1] = f2bf(s0y * inv);
      m[2] = f2bf(s0z * inv); m[3] = f2bf(s0w * inv);
      m[4] = f2bf(s1x * inv); m[5] = f2bf(s1y * inv);
      m[6] = f2bf(s1z * inv); m[7] = f2bf(s1w * inv);
      *(us8*)vd = m;
      stage8(&sV[nl * 72 + 32 + l4 * 8], atoms + (size_t)n * 32 + l4 * 8);
    } else {
      us8 z = {0, 0, 0, 0, 0, 0, 0, 0};
      *(us8*)vd = z;
      *(us8*)&sV[nl * 72 + 32 + l4 * 8] = z;
    }
  }
  __syncthreads();

  const int cl = lane & 15, q = lane >> 4;
  const int nt = wv * 16;
  const int ng = n0 + nt + cl;

  // ---- GEMM1: K=64 ----
  bfrag8 vb0 = *(const bfrag8*)&sV[(nt + cl) * 72 + q * 8];
  bfrag8 vb1 = *(const bfrag8*)&sV[(nt + cl) * 72 + 32 + q * 8];
#pragma unroll
  for (int rt = 0; rt < 8; ++rt) {
    f32x4 acc = {0.f, 0.f, 0.f, 0.f};
    acc = mfma16(*(const bfrag8*)&sW[(q * 128 + rt * 16 + cl) * 8], vb0, acc);
    acc = mfma16(*(const bfrag8*)&sW[4096 + (q * 128 + rt * 16 + cl) * 8], vb1, acc);
    const int c0 = rt * 16 + q * 4;
    us4 hv;
#pragma unroll
    for (int r = 0; r < 4; ++r) {
      float v = acc[r] + sB1[c0 + r];
      hv[r] = f2bf(fmaxf(v, 0.f));
    }
    *(us4*)&sH1[(nt + cl) * 136 + c0] = hv;
  }
  __syncthreads();

  // ---- GEMM2: K=128 ----
  bfrag8 hb[4];
  {
    const unsigned short* hr = &sH1[(nt + cl) * 136 + q * 8];
#pragma unroll
    for (int ks = 0; ks < 4; ++ks) hb[ks] = *(const bfrag8*)(hr + ks * 32);
  }
#pragma unroll
  for (int rt = 0; rt < 4; ++rt) {
    f32x4 acc = {0.f, 0.f, 0.f, 0.f};
#pragma unroll
    for (int ks = 0; ks < 4; ++ks)
      acc = mfma16(*(const bfrag8*)&sW[8192 + ks * 2048 + (q * 64 + rt * 16 + cl) * 8], hb[ks], acc);
    const int c0 = rt * 16 + q * 4;
    us4 hv;
#pragma unroll
    for (int r = 0; r < 4; ++r) {
      float v = acc[r] + sB2[c0 + r];
      hv[r] = f2bf(fmaxf(v, 0.f));
    }
    *(us4*)&sV[(nt + cl) * 72 + c0] = hv;   // reuse sV as h2
  }
  __syncthreads();

  // ---- GEMM3: K=64, no relu ----
  bfrag8 gb0 = *(const bfrag8*)&sV[(nt + cl) * 72 + q * 8];
  bfrag8 gb1 = *(const bfrag8*)&sV[(nt + cl) * 72 + 32 + q * 8];
  if (ng < NN) {
    float* outp = new_atoms + (size_t)ng * 32;
#pragma unroll
    for (int rt = 0; rt < 2; ++rt) {
      f32x4 acc = {0.f, 0.f, 0.f, 0.f};
      acc = mfma16(*(const bfrag8*)&sW[16384 + (q * 32 + rt * 16 + cl) * 8], gb0, acc);
      acc = mfma16(*(const bfrag8*)&sW[16384 + 1024 + (q * 32 + rt * 16 + cl) * 8], gb1, acc);
      const int c0 = rt * 16 + q * 4;
      float4 o;
      o.x = acc[0] + sB3[c0 + 0];
      o.y = acc[1] + sB3[c0 + 1];
      o.z = acc[2] + sB3[c0 + 2];
      o.w = acc[3] + sB3[c0 + 3];
      *(float4*)(outp + c0) = o;
    }
  }
}

extern "C" void kernel_launch(void* const* d_in, const int* in_sizes, int n_in,
                              void* d_out, int out_size, void* d_ws, size_t ws_size,
                              hipStream_t stream) {
  const float* bonds = (const float*)d_in[0];
  const int* a1 = (const int*)d_in[1];
  const int* a2 = (const int*)d_in[2];
  const float* atoms = (const float*)d_in[3];
  const float* We1 = (const float*)d_in[4];
  const float* be1 = (const float*)d_in[5];
  const float* We2 = (const float*)d_in[6];
  const float* be2 = (const float*)d_in[7];
  const float* We3 = (const float*)d_in[8];
  const float* be3 = (const float*)d_in[9];
  const float* Wv1 = (const float*)d_in[10];
  const float* bv1 = (const float*)d_in[11];
  const float* Wv2 = (const float*)d_in[12];
  const float* bv2 = (const float*)d_in[13];
  const float* Wv3 = (const float*)d_in[14];
  const float* bv3 = (const float*)d_in[15];

  float* out = (float*)d_out;
  float* new_atoms = out;                       // [NN*32]
  float* new_bonds = out + (size_t)NN * 32;     // [NE*32]

  char* ws = (char*)d_ws;
  int* cnt    = (int*)(ws + 0);                 // [NN]
  int* off    = (int*)(ws + 400000);            // [NN+1]
  int* cursor = (int*)(ws + 800016);            // [NN]
  int* bsum   = (int*)(ws + 1200064);           // [512]
  unsigned short* wp = (unsigned short*)(ws + 1202176);  // packed bf16 weights (81920 B)
  int* csr    = (int*)(ws + 1284096);           // [NE]

  hipMemsetAsync(cnt, 0, (size_t)NN * 4, stream);

  pack_w<<<48, 256, 0, stream>>>(We1, wp + 0, 96, 128);
  pack_w<<<32, 256, 0, stream>>>(We2, wp + 12288, 128, 64);
  pack_w<<<8, 256, 0, stream>>>(We3, wp + 20480, 64, 32);
  pack_w<<<32, 256, 0, stream>>>(Wv1, wp + 22528, 64, 128);
  pack_w<<<32, 256, 0, stream>>>(Wv2, wp + 30720, 128, 64);
  pack_w<<<8, 256, 0, stream>>>(Wv3, wp + 38912, 64, 32);

  // CSR build
  count_k<<<(NE + 255) / 256, 256, 0, stream>>>(a2, cnt);
  scan_blocks<<<NB_SCAN, 256, 0, stream>>>(cnt, off, bsum);
  scan_bsum<<<1, 512, 0, stream>>>(bsum);
  scan_finalize<<<NB_SCAN, 256, 0, stream>>>(off, bsum, cursor);
  fill_csr<<<(NE + 255) / 256, 256, 0, stream>>>(a2, cursor, csr);

  edge_kernel<<<NE / 128, 256, 0, stream>>>(bonds, a1, a2, atoms, be1, be2, be3, wp,
                                            new_bonds);
  node_kernel<<<(NN + 63) / 64, 256, 0, stream>>>(atoms, bv1, bv2, bv3, wp + 22528,
                                                  off, csr, new_bonds, new_atoms);
}

// Round 5
// 437.227 us; speedup vs baseline: 1.8579x; 1.0438x over previous
//
#include <hip/hip_runtime.h>
#include <hip/hip_bf16.h>

#define NN 100000
#define NE 1600000
#define NB_SCAN 391   // ceil(NN/256)
#define ETILES 12500  // NE/128
#define EGRID 512
#define NGRID 512

typedef __attribute__((ext_vector_type(8))) short bfrag8;   // 8 bf16 (4 VGPRs) MFMA operand
typedef __attribute__((ext_vector_type(4))) float f32x4;    // MFMA accumulator
typedef __attribute__((ext_vector_type(8))) unsigned short us8;
typedef __attribute__((ext_vector_type(4))) unsigned int u32x4;

__device__ __forceinline__ unsigned short f2bf(float f) {
  unsigned int u = __float_as_uint(f);
  u += 0x7fffu + ((u >> 16) & 1u);   // RNE
  return (unsigned short)(u >> 16);
}

// packed 2x f32 -> 2x bf16 in one u32 (no builtin on gfx950 -> inline asm, RNE)
__device__ __forceinline__ unsigned int pk2(float a, float b) {
  unsigned int r;
  asm("v_cvt_pk_bf16_f32 %0, %1, %2" : "=v"(r) : "v"(a), "v"(b));
  return r;
}

__device__ __forceinline__ uint2 pk4(float v0, float v1, float v2, float v3) {
  return make_uint2(pk2(v0, v1), pk2(v2, v3));
}

__device__ __forceinline__ bfrag8 pack8(float4 a, float4 b) {
  union { u32x4 u; bfrag8 f; } c;
  c.u[0] = pk2(a.x, a.y); c.u[1] = pk2(a.z, a.w);
  c.u[2] = pk2(b.x, b.y); c.u[3] = pk2(b.z, b.w);
  return c.f;
}

__device__ __forceinline__ bfrag8 as_frag(us8 v) {
  union { us8 u; bfrag8 f; } c;
  c.u = v;
  return c.f;
}

__device__ __forceinline__ f32x4 mfma16(bfrag8 a, bfrag8 b, f32x4 c) {
  return __builtin_amdgcn_mfma_f32_16x16x32_bf16(a, b, c, 0, 0, 0);
}

__device__ __forceinline__ void gload_lds16(const void* g, void* l) {
  __builtin_amdgcn_global_load_lds(
      (const __attribute__((address_space(1))) unsigned int*)g,
      (__attribute__((address_space(3))) unsigned int*)l, 16, 0, 0);
}

// atoms f32 -> bf16 (stream)
__global__ void cvt_atoms(const float* __restrict__ src, unsigned short* __restrict__ dst) {
  int i = blockIdx.x * 256 + threadIdx.x;   // one float4 per thread
  float4 v = *(const float4*)(src + (size_t)i * 4);
  *(uint2*)(dst + (size_t)i * 4) = pk4(v.x, v.y, v.z, v.w);
}

// Pack W[K][N] f32 row-major -> Wp[g][c][j] bf16 with k = g*8+j (fragment-linear)
__global__ void pack_w(const float* __restrict__ src, unsigned short* __restrict__ dst,
                       int K, int N) {
  int i = blockIdx.x * 256 + threadIdx.x;
  if (i >= K * N) return;
  int j = i & 7;
  int gc = i >> 3;        // g*N + c
  int c = gc % N;
  int g = gc / N;
  dst[i] = f2bf(src[(g * 8 + j) * N + c]);
}

// ---------------- CSR construction ----------------
__global__ void count_k(const int* __restrict__ a2, int* __restrict__ cnt) {
  int e = blockIdx.x * 256 + threadIdx.x;
  if (e < NE) atomicAdd(&cnt[a2[e]], 1);
}

__global__ void scan_blocks(const int* __restrict__ cnt, int* __restrict__ off,
                            int* __restrict__ bsum) {
  __shared__ int s[256];
  const int t = threadIdx.x;
  const int idx = blockIdx.x * 256 + t;
  int v = (idx < NN) ? cnt[idx] : 0;
  s[t] = v;
  __syncthreads();
  for (int d = 1; d < 256; d <<= 1) {
    int x = (t >= d) ? s[t - d] : 0;
    __syncthreads();
    s[t] += x;
    __syncthreads();
  }
  if (idx < NN) off[idx] = s[t] - v;          // exclusive within block
  if (t == 255) bsum[blockIdx.x] = s[255];
}

__global__ void scan_bsum(int* __restrict__ bsum) {   // single block of 512
  __shared__ int s[512];
  const int t = threadIdx.x;
  int v = (t < NB_SCAN) ? bsum[t] : 0;
  s[t] = v;
  __syncthreads();
  for (int d = 1; d < 512; d <<= 1) {
    int x = (t >= d) ? s[t - d] : 0;
    __syncthreads();
    s[t] += x;
    __syncthreads();
  }
  if (t < NB_SCAN) bsum[t] = s[t] - v;        // exclusive block bases
}

__global__ void scan_finalize(int* __restrict__ off, const int* __restrict__ bsum,
                              int* __restrict__ cursor) {
  int idx = blockIdx.x * 256 + threadIdx.x;
  if (idx < NN) {
    int o = off[idx] + bsum[blockIdx.x];
    off[idx] = o;
    cursor[idx] = o;
  }
  if (idx == 0) off[NN] = NE;
}

__global__ void fill_csr(const int* __restrict__ a2, int* __restrict__ cursor,
                         int* __restrict__ csr) {
  int e = blockIdx.x * 256 + threadIdx.x;
  if (e < NE) {
    int p = atomicAdd(&cursor[a2[e]], 1);
    csr[p] = e;
  }
}

// ---------------- Edge kernel: persistent, 128 edges/tile, 1-tile pipeline ----------------
__global__ __launch_bounds__(256, 2) void edge_kernel(
    const float* __restrict__ bonds, const int* __restrict__ a1p, const int* __restrict__ a2p,
    const unsigned short* __restrict__ atoms_bf,
    const float* __restrict__ be1, const float* __restrict__ be2, const float* __restrict__ be3,
    const unsigned short* __restrict__ wpack,
    float* __restrict__ new_bonds) {
  __shared__ unsigned short sW[22528];          // We1p[12288] We2p[8192] We3p[2048] = 45056 B
  __shared__ float sB1[128], sB2[64], sB3[32];
  __shared__ unsigned short sH1[128 * 136];     // h1 [128][128] pad->136; aliased as h2 [128][72]

  const int tid = threadIdx.x;
  const int lane = tid & 63, wv = tid >> 6;
  const int cl = lane & 15, q = lane >> 4;
  const int esub = wv * 32 + cl;                // + t*16

  // ---- stage weights ONCE (async DMA) + biases
  {
    const char* src = (const char*)wpack;
    char* dst = (char*)sW;
#pragma unroll
    for (int i = 0; i < 11; ++i) {
      const int c = i * 4 + wv;
      gload_lds16(src + c * 1024 + lane * 16, dst + c * 1024);
    }
  }
  if (tid < 128) sB1[tid] = be1[tid];
  else if (tid < 192) sB2[tid - 128] = be2[tid - 128];
  else if (tid < 224) sB3[tid - 192] = be3[tid - 192];

  int tile = blockIdx.x;
  us8 ra1[2], ra2[2];      // atom bf16 frags (raw)
  float4 rb[2][2];         // bond f32 raw
  int ia1n[2], ia2n[2];    // indices for NEXT tile

  // ---- prologue: gather tile0; indices for tile0+G
#pragma unroll
  for (int t = 0; t < 2; ++t) {
    const int e = tile * 128 + esub + t * 16;
    const int ia1 = a1p[e], ia2 = a2p[e];
    ra1[t] = *(const us8*)(atoms_bf + (size_t)ia1 * 32 + q * 8);
    ra2[t] = *(const us8*)(atoms_bf + (size_t)ia2 * 32 + q * 8);
    const float* bp = bonds + (size_t)e * 32 + q * 8;
    rb[t][0] = *(const float4*)(bp);
    rb[t][1] = *(const float4*)(bp + 4);
  }
  {
    int tn = tile + EGRID; if (tn >= ETILES) tn = tile;
#pragma unroll
    for (int t = 0; t < 2; ++t) {
      const int e = tn * 128 + esub + t * 16;
      ia1n[t] = a1p[e]; ia2n[t] = a2p[e];
    }
  }
  __syncthreads();   // weights + biases staged

  for (; tile < ETILES; tile += EGRID) {
    // ---- convert current frags (frees ra/rb)
    bfrag8 xb0[2], xb1[2], xb2[2];
#pragma unroll
    for (int t = 0; t < 2; ++t) {
      xb0[t] = as_frag(ra1[t]);
      xb1[t] = as_frag(ra2[t]);
      xb2[t] = pack8(rb[t][0], rb[t][1]);
    }
    // ---- issue next tile's gathers (indices already resident), then next-next indices
    const int tn = (tile + EGRID < ETILES) ? tile + EGRID : tile;
#pragma unroll
    for (int t = 0; t < 2; ++t) {
      ra1[t] = *(const us8*)(atoms_bf + (size_t)ia1n[t] * 32 + q * 8);
      ra2[t] = *(const us8*)(atoms_bf + (size_t)ia2n[t] * 32 + q * 8);
      const int e = tn * 128 + esub + t * 16;
      const float* bp = bonds + (size_t)e * 32 + q * 8;
      rb[t][0] = *(const float4*)(bp);
      rb[t][1] = *(const float4*)(bp + 4);
    }
    {
      int tnn = tile + 2 * EGRID; if (tnn >= ETILES) tnn = tn;
#pragma unroll
      for (int t = 0; t < 2; ++t) {
        const int e = tnn * 128 + esub + t * 16;
        ia1n[t] = a1p[e]; ia2n[t] = a2p[e];
      }
    }

    // ---- GEMM1: h1^T[128][16x2] = We1^T[128x96] @ x^T ----
#pragma unroll
    for (int rt = 0; rt < 8; ++rt) {
      const unsigned short* wa = &sW[(q * 128 + rt * 16 + cl) * 8];
      bfrag8 w0 = *(const bfrag8*)(wa);
      bfrag8 w1 = *(const bfrag8*)(wa + 4096);
      bfrag8 w2 = *(const bfrag8*)(wa + 8192);
      f32x4 acc[2];
      acc[0] = (f32x4){0.f, 0.f, 0.f, 0.f};
      acc[1] = (f32x4){0.f, 0.f, 0.f, 0.f};
#pragma unroll
      for (int t = 0; t < 2; ++t) {
        acc[t] = mfma16(w0, xb0[t], acc[t]);
        acc[t] = mfma16(w1, xb1[t], acc[t]);
        acc[t] = mfma16(w2, xb2[t], acc[t]);
      }
      const int c0 = rt * 16 + q * 4;
#pragma unroll
      for (int t = 0; t < 2; ++t) {
        uint2 hv = pk4(fmaxf(acc[t][0] + sB1[c0 + 0], 0.f),
                       fmaxf(acc[t][1] + sB1[c0 + 1], 0.f),
                       fmaxf(acc[t][2] + sB1[c0 + 2], 0.f),
                       fmaxf(acc[t][3] + sB1[c0 + 3], 0.f));
        *(uint2*)&sH1[(esub + t * 16) * 136 + c0] = hv;
      }
    }
    __syncthreads();   // h1 complete

    // ---- GEMM2: h2^T[64][16x2] = We2^T[64x128] @ h1^T ----
    bfrag8 hb[4][2];
#pragma unroll
    for (int t = 0; t < 2; ++t) {
      const unsigned short* hr = &sH1[(esub + t * 16) * 136 + q * 8];
#pragma unroll
      for (int ks = 0; ks < 4; ++ks) hb[ks][t] = *(const bfrag8*)(hr + ks * 32);
    }
    __syncthreads();   // h1 reads done -> safe to overwrite as h2

    unsigned short* sH2 = sH1;   // stride 72
#pragma unroll
    for (int rt = 0; rt < 4; ++rt) {
      f32x4 acc[2];
      acc[0] = (f32x4){0.f, 0.f, 0.f, 0.f};
      acc[1] = (f32x4){0.f, 0.f, 0.f, 0.f};
#pragma unroll
      for (int ks = 0; ks < 4; ++ks) {
        bfrag8 w = *(const bfrag8*)&sW[12288 + ks * 2048 + (q * 64 + rt * 16 + cl) * 8];
#pragma unroll
        for (int t = 0; t < 2; ++t) acc[t] = mfma16(w, hb[ks][t], acc[t]);
      }
      const int c0 = rt * 16 + q * 4;
#pragma unroll
      for (int t = 0; t < 2; ++t) {
        uint2 hv = pk4(fmaxf(acc[t][0] + sB2[c0 + 0], 0.f),
                       fmaxf(acc[t][1] + sB2[c0 + 1], 0.f),
                       fmaxf(acc[t][2] + sB2[c0 + 2], 0.f),
                       fmaxf(acc[t][3] + sB2[c0 + 3], 0.f));
        *(uint2*)&sH2[(esub + t * 16) * 72 + c0] = hv;
      }
    }
    __syncthreads();   // h2 complete

    // ---- GEMM3: out^T[32][16x2] = We3^T[32x64] @ h2^T ----
    bfrag8 gb0[2], gb1[2];
#pragma unroll
    for (int t = 0; t < 2; ++t) {
      const unsigned short* hr = &sH2[(esub + t * 16) * 72 + q * 8];
      gb0[t] = *(const bfrag8*)(hr);
      gb1[t] = *(const bfrag8*)(hr + 32);
    }
#pragma unroll
    for (int rt = 0; rt < 2; ++rt) {
      bfrag8 w0 = *(const bfrag8*)&sW[20480 + (q * 32 + rt * 16 + cl) * 8];
      bfrag8 w1 = *(const bfrag8*)&sW[20480 + 1024 + (q * 32 + rt * 16 + cl) * 8];
      const int c0 = rt * 16 + q * 4;
#pragma unroll
      for (int t = 0; t < 2; ++t) {
        f32x4 acc = {0.f, 0.f, 0.f, 0.f};
        acc = mfma16(w0, gb0[t], acc);
        acc = mfma16(w1, gb1[t], acc);
        const int e = tile * 128 + esub + t * 16;
        float4 o;
        o.x = acc[0] + sB3[c0 + 0];
        o.y = acc[1] + sB3[c0 + 1];
        o.z = acc[2] + sB3[c0 + 2];
        o.w = acc[3] + sB3[c0 + 3];
        *(float4*)(new_bonds + (size_t)e * 32 + c0) = o;
      }
    }
    __syncthreads();   // gb reads done -> next tile may overwrite sH1/sH2
  }
}

// ---------------- Node kernel: persistent, 64 nodes/tile, CSR gather-mean + MLP -------
__global__ __launch_bounds__(256, 2) void node_kernel(
    const unsigned short* __restrict__ atoms_bf,
    const float* __restrict__ bv1, const float* __restrict__ bv2, const float* __restrict__ bv3,
    const unsigned short* __restrict__ wpack,
    const int* __restrict__ off, const int* __restrict__ csr,
    const float* __restrict__ new_bonds, float* __restrict__ new_atoms) {
  __shared__ unsigned short sW[18432];          // Wv1p[8192] Wv2p[8192] Wv3p[2048]
  __shared__ float sB1[128], sB2[64], sB3[32];
  __shared__ unsigned short sV[64 * 72];        // v_in [64][64] pad->72; reused as h2
  __shared__ unsigned short sH1[64 * 136];

  const int tid = threadIdx.x;
  const int lane = tid & 63, wv = tid >> 6;
  const int cl = lane & 15, q = lane >> 4;
  const int nl = tid >> 2, l4 = tid & 3;

  {
    const uint4* src = (const uint4*)wpack;
    uint4* dst = (uint4*)sW;
#pragma unroll
    for (int i = 0; i < 9; ++i) dst[tid + i * 256] = src[tid + i * 256];
  }
  if (tid < 128) sB1[tid] = bv1[tid];
  if (tid < 64) sB2[tid] = bv2[tid];
  if (tid < 32) sB3[tid] = bv3[tid];

  for (int n0 = blockIdx.x * 64; n0 < NN; n0 += NGRID * 64) {
    __syncthreads();   // weights staged / previous tile's LDS reads complete

    // stage v tile: cols [0,32) = mean_bonds (CSR gather), [32,64) = atoms (bf16 copy)
    {
      const int n = n0 + nl;
      unsigned short* vd = &sV[nl * 72 + l4 * 8];
      if (n < NN) {
        const int o0 = off[n], o1 = off[n + 1];
        float4 sa0 = {0.f, 0.f, 0.f, 0.f}, sa1 = {0.f, 0.f, 0.f, 0.f};
        float4 sb0 = {0.f, 0.f, 0.f, 0.f}, sb1 = {0.f, 0.f, 0.f, 0.f};
        int i = o0;
        for (; i + 1 < o1; i += 2) {           // unroll-2: 4 float4 in flight
          const int ea = csr[i], eb = csr[i + 1];
          const float4* pa = (const float4*)(new_bonds + (size_t)ea * 32 + l4 * 8);
          const float4* pb = (const float4*)(new_bonds + (size_t)eb * 32 + l4 * 8);
          float4 a0 = pa[0], a1 = pa[1];
          float4 b0 = pb[0], b1 = pb[1];
          sa0.x += a0.x; sa0.y += a0.y; sa0.z += a0.z; sa0.w += a0.w;
          sa1.x += a1.x; sa1.y += a1.y; sa1.z += a1.z; sa1.w += a1.w;
          sb0.x += b0.x; sb0.y += b0.y; sb0.z += b0.z; sb0.w += b0.w;
          sb1.x += b1.x; sb1.y += b1.y; sb1.z += b1.z; sb1.w += b1.w;
        }
        if (i < o1) {
          const int ea = csr[i];
          const float4* pa = (const float4*)(new_bonds + (size_t)ea * 32 + l4 * 8);
          float4 a0 = pa[0], a1 = pa[1];
          sa0.x += a0.x; sa0.y += a0.y; sa0.z += a0.z; sa0.w += a0.w;
          sa1.x += a1.x; sa1.y += a1.y; sa1.z += a1.z; sa1.w += a1.w;
        }
        const float inv = 1.0f / fmaxf((float)(o1 - o0), 1.0f);
        uint4 m;
        m.x = pk2((sa0.x + sb0.x) * inv, (sa0.y + sb0.y) * inv);
        m.y = pk2((sa0.z + sb0.z) * inv, (sa0.w + sb0.w) * inv);
        m.z = pk2((sa1.x + sb1.x) * inv, (sa1.y + sb1.y) * inv);
        m.w = pk2((sa1.z + sb1.z) * inv, (sa1.w + sb1.w) * inv);
        *(uint4*)vd = m;
        *(us8*)&sV[nl * 72 + 32 + l4 * 8] =
            *(const us8*)(atoms_bf + (size_t)n * 32 + l4 * 8);
      } else {
        us8 z = {0, 0, 0, 0, 0, 0, 0, 0};
        *(us8*)vd = z;
        *(us8*)&sV[nl * 72 + 32 + l4 * 8] = z;
      }
    }
    __syncthreads();

    const int nt = wv * 16;
    const int ng = n0 + nt + cl;

    // ---- GEMM1: K=64 ----
    bfrag8 vb0 = *(const bfrag8*)&sV[(nt + cl) * 72 + q * 8];
    bfrag8 vb1 = *(const bfrag8*)&sV[(nt + cl) * 72 + 32 + q * 8];
#pragma unroll
    for (int rt = 0; rt < 8; ++rt) {
      f32x4 acc = {0.f, 0.f, 0.f, 0.f};
      acc = mfma16(*(const bfrag8*)&sW[(q * 128 + rt * 16 + cl) * 8], vb0, acc);
      acc = mfma16(*(const bfrag8*)&sW[4096 + (q * 128 + rt * 16 + cl) * 8], vb1, acc);
      const int c0 = rt * 16 + q * 4;
      uint2 hv = pk4(fmaxf(acc[0] + sB1[c0 + 0], 0.f),
                     fmaxf(acc[1] + sB1[c0 + 1], 0.f),
                     fmaxf(acc[2] + sB1[c0 + 2], 0.f),
                     fmaxf(acc[3] + sB1[c0 + 3], 0.f));
      *(uint2*)&sH1[(nt + cl) * 136 + c0] = hv;
    }
    __syncthreads();

    // ---- GEMM2: K=128 ----
    bfrag8 hb[4];
    {
      const unsigned short* hr = &sH1[(nt + cl) * 136 + q * 8];
#pragma unroll
      for (int ks = 0; ks < 4; ++ks) hb[ks] = *(const bfrag8*)(hr + ks * 32);
    }
    __syncthreads();   // h1 reads done -> overwrite sV as h2
#pragma unroll
    for (int rt = 0; rt < 4; ++rt) {
      f32x4 acc = {0.f, 0.f, 0.f, 0.f};
#pragma unroll
      for (int ks = 0; ks < 4; ++ks)
        acc = mfma16(*(const bfrag8*)&sW[8192 + ks * 2048 + (q * 64 + rt * 16 + cl) * 8], hb[ks], acc);
      const int c0 = rt * 16 + q * 4;
      uint2 hv = pk4(fmaxf(acc[0] + sB2[c0 + 0], 0.f),
                     fmaxf(acc[1] + sB2[c0 + 1], 0.f),
                     fmaxf(acc[2] + sB2[c0 + 2], 0.f),
                     fmaxf(acc[3] + sB2[c0 + 3], 0.f));
      *(uint2*)&sV[(nt + cl) * 72 + c0] = hv;   // reuse sV as h2
    }
    __syncthreads();

    // ---- GEMM3: K=64, no relu ----
    bfrag8 gb0 = *(const bfrag8*)&sV[(nt + cl) * 72 + q * 8];
    bfrag8 gb1 = *(const bfrag8*)&sV[(nt + cl) * 72 + 32 + q * 8];
    if (ng < NN) {
      float* outp = new_atoms + (size_t)ng * 32;
#pragma unroll
      for (int rt = 0; rt < 2; ++rt) {
        f32x4 acc = {0.f, 0.f, 0.f, 0.f};
        acc = mfma16(*(const bfrag8*)&sW[16384 + (q * 32 + rt * 16 + cl) * 8], gb0, acc);
        acc = mfma16(*(const bfrag8*)&sW[16384 + 1024 + (q * 32 + rt * 16 + cl) * 8], gb1, acc);
        const int c0 = rt * 16 + q * 4;
        float4 o;
        o.x = acc[0] + sB3[c0 + 0];
        o.y = acc[1] + sB3[c0 + 1];
        o.z = acc[2] + sB3[c0 + 2];
        o.w = acc[3] + sB3[c0 + 3];
        *(float4*)(outp + c0) = o;
      }
    }
  }
}

extern "C" void kernel_launch(void* const* d_in, const int* in_sizes, int n_in,
                              void* d_out, int out_size, void* d_ws, size_t ws_size,
                              hipStream_t stream) {
  const float* bonds = (const float*)d_in[0];
  const int* a1 = (const int*)d_in[1];
  const int* a2 = (const int*)d_in[2];
  const float* atoms = (const float*)d_in[3];
  const float* We1 = (const float*)d_in[4];
  const float* be1 = (const float*)d_in[5];
  const float* We2 = (const float*)d_in[6];
  const float* be2 = (const float*)d_in[7];
  const float* We3 = (const float*)d_in[8];
  const float* be3 = (const float*)d_in[9];
  const float* Wv1 = (const float*)d_in[10];
  const float* bv1 = (const float*)d_in[11];
  const float* Wv2 = (const float*)d_in[12];
  const float* bv2 = (const float*)d_in[13];
  const float* Wv3 = (const float*)d_in[14];
  const float* bv3 = (const float*)d_in[15];

  float* out = (float*)d_out;
  float* new_atoms = out;                       // [NN*32]
  float* new_bonds = out + (size_t)NN * 32;     // [NE*32]

  char* ws = (char*)d_ws;
  int* cnt    = (int*)(ws + 0);                 // [NN], reused as fill cursor
  int* off    = (int*)(ws + 400000);            // [NN+1]
  int* bsum   = (int*)(ws + 800016);            // [512]
  unsigned short* wp = (unsigned short*)(ws + 802064);        // packed bf16 weights (81920 B)
  int* csr    = (int*)(ws + 883984);            // [NE] (6.4 MB)
  unsigned short* atoms_bf = (unsigned short*)(ws + 7283984); // [NN*32] bf16 (6.4 MB)

  hipMemsetAsync(cnt, 0, (size_t)NN * 4, stream);

  cvt_atoms<<<3125, 256, 0, stream>>>(atoms, atoms_bf);

  pack_w<<<48, 256, 0, stream>>>(We1, wp + 0, 96, 128);
  pack_w<<<32, 256, 0, stream>>>(We2, wp + 12288, 128, 64);
  pack_w<<<8, 256, 0, stream>>>(We3, wp + 20480, 64, 32);
  pack_w<<<32, 256, 0, stream>>>(Wv1, wp + 22528, 64, 128);
  pack_w<<<32, 256, 0, stream>>>(Wv2, wp + 30720, 128, 64);
  pack_w<<<8, 256, 0, stream>>>(Wv3, wp + 38912, 64, 32);

  // CSR build
  count_k<<<(NE + 255) / 256, 256, 0, stream>>>(a2, cnt);
  scan_blocks<<<NB_SCAN, 256, 0, stream>>>(cnt, off, bsum);
  scan_bsum<<<1, 512, 0, stream>>>(bsum);
  scan_finalize<<<NB_SCAN, 256, 0, stream>>>(off, bsum, cnt);   // cursor := cnt
  fill_csr<<<(NE + 255) / 256, 256, 0, stream>>>(a2, cnt, csr);

  edge_kernel<<<EGRID, 256, 0, stream>>>(bonds, a1, a2, atoms_bf, be1, be2, be3, wp,
                                         new_bonds);
  node_kernel<<<NGRID, 256, 0, stream>>>(atoms_bf, bv1, bv2, bv3, wp + 22528,
                                         off, csr, new_bonds, new_atoms);
}

// Round 6
// 428.307 us; speedup vs baseline: 1.8966x; 1.0208x over previous
//
#include <hip/hip_runtime.h>
#include <hip/hip_bf16.h>

#define NN 100000
#define NE 1600000
#define NB_SCAN 391   // ceil(NN/256)
#define ETILES 12500  // NE/128
#define EGRID 512
#define NGRID 1024

typedef __attribute__((ext_vector_type(8))) short bfrag8;   // 8 bf16 (4 VGPRs) MFMA operand
typedef __attribute__((ext_vector_type(4))) float f32x4;    // MFMA accumulator
typedef __attribute__((ext_vector_type(8))) unsigned short us8;
typedef __attribute__((ext_vector_type(4))) unsigned int u32x4;

__device__ __forceinline__ unsigned short f2bf(float f) {
  unsigned int u = __float_as_uint(f);
  u += 0x7fffu + ((u >> 16) & 1u);   // RNE
  return (unsigned short)(u >> 16);
}

// packed 2x f32 -> 2x bf16 in one u32 (no builtin on gfx950 -> inline asm, RNE)
__device__ __forceinline__ unsigned int pk2(float a, float b) {
  unsigned int r;
  asm("v_cvt_pk_bf16_f32 %0, %1, %2" : "=v"(r) : "v"(a), "v"(b));
  return r;
}

__device__ __forceinline__ uint2 pk4(float v0, float v1, float v2, float v3) {
  return make_uint2(pk2(v0, v1), pk2(v2, v3));
}

__device__ __forceinline__ bfrag8 pack8(float4 a, float4 b) {
  union { u32x4 u; bfrag8 f; } c;
  c.u[0] = pk2(a.x, a.y); c.u[1] = pk2(a.z, a.w);
  c.u[2] = pk2(b.x, b.y); c.u[3] = pk2(b.z, b.w);
  return c.f;
}

__device__ __forceinline__ bfrag8 as_frag(us8 v) {
  union { us8 u; bfrag8 f; } c;
  c.u = v;
  return c.f;
}

__device__ __forceinline__ f32x4 mfma16(bfrag8 a, bfrag8 b, f32x4 c) {
  return __builtin_amdgcn_mfma_f32_16x16x32_bf16(a, b, c, 0, 0, 0);
}

__device__ __forceinline__ void gload_lds16(const void* g, void* l) {
  __builtin_amdgcn_global_load_lds(
      (const __attribute__((address_space(1))) unsigned int*)g,
      (__attribute__((address_space(3))) unsigned int*)l, 16, 0, 0);
}

// atoms f32 -> bf16 (stream)
__global__ void cvt_atoms(const float* __restrict__ src, unsigned short* __restrict__ dst) {
  int i = blockIdx.x * 256 + threadIdx.x;   // one float4 per thread
  float4 v = *(const float4*)(src + (size_t)i * 4);
  *(uint2*)(dst + (size_t)i * 4) = pk4(v.x, v.y, v.z, v.w);
}

// Pack W[K][N] f32 row-major -> Wp[g][c][j] bf16 with k = g*8+j (fragment-linear)
__global__ void pack_w(const float* __restrict__ src, unsigned short* __restrict__ dst,
                       int K, int N) {
  int i = blockIdx.x * 256 + threadIdx.x;
  if (i >= K * N) return;
  int j = i & 7;
  int gc = i >> 3;        // g*N + c
  int c = gc % N;
  int g = gc / N;
  dst[i] = f2bf(src[(g * 8 + j) * N + c]);
}

// ---------------- CSR construction ----------------
__global__ void count_k(const int* __restrict__ a2, int* __restrict__ cnt) {
  int e = blockIdx.x * 256 + threadIdx.x;
  if (e < NE) atomicAdd(&cnt[a2[e]], 1);
}

__global__ void scan_blocks(const int* __restrict__ cnt, int* __restrict__ off,
                            int* __restrict__ bsum) {
  __shared__ int s[256];
  const int t = threadIdx.x;
  const int idx = blockIdx.x * 256 + t;
  int v = (idx < NN) ? cnt[idx] : 0;
  s[t] = v;
  __syncthreads();
  for (int d = 1; d < 256; d <<= 1) {
    int x = (t >= d) ? s[t - d] : 0;
    __syncthreads();
    s[t] += x;
    __syncthreads();
  }
  if (idx < NN) off[idx] = s[t] - v;          // exclusive within block
  if (t == 255) bsum[blockIdx.x] = s[255];
}

__global__ void scan_bsum(int* __restrict__ bsum) {   // single block of 512
  __shared__ int s[512];
  const int t = threadIdx.x;
  int v = (t < NB_SCAN) ? bsum[t] : 0;
  s[t] = v;
  __syncthreads();
  for (int d = 1; d < 512; d <<= 1) {
    int x = (t >= d) ? s[t - d] : 0;
    __syncthreads();
    s[t] += x;
    __syncthreads();
  }
  if (t < NB_SCAN) bsum[t] = s[t] - v;        // exclusive block bases
}

__global__ void scan_finalize(int* __restrict__ off, const int* __restrict__ bsum,
                              int* __restrict__ cursor) {
  int idx = blockIdx.x * 256 + threadIdx.x;
  if (idx < NN) {
    int o = off[idx] + bsum[blockIdx.x];
    off[idx] = o;
    cursor[idx] = o;
  }
  if (idx == 0) off[NN] = NE;
}

__global__ void fill_csr(const int* __restrict__ a2, int* __restrict__ cursor,
                         int* __restrict__ csr) {
  int e = blockIdx.x * 256 + threadIdx.x;
  if (e < NE) {
    int p = atomicAdd(&cursor[a2[e]], 1);
    csr[p] = e;
  }
}

// ---------------- Edge kernel: persistent, 128 edges/tile, 1-tile pipeline ----------------
__global__ __launch_bounds__(256, 2) void edge_kernel(
    const float* __restrict__ bonds, const int* __restrict__ a1p, const int* __restrict__ a2p,
    const unsigned short* __restrict__ atoms_bf,
    const float* __restrict__ be1, const float* __restrict__ be2, const float* __restrict__ be3,
    const unsigned short* __restrict__ wpack,
    float* __restrict__ new_bonds) {
  __shared__ unsigned short sW[22528];          // We1p[12288] We2p[8192] We3p[2048] = 45056 B
  __shared__ float sB1[128], sB2[64], sB3[32];
  __shared__ unsigned short sH1[128 * 136];     // h1 [128][128] pad->136; aliased as h2 [128][72]

  const int tid = threadIdx.x;
  const int lane = tid & 63, wv = tid >> 6;
  const int cl = lane & 15, q = lane >> 4;
  const int esub = wv * 32 + cl;                // + t*16

  // ---- stage weights ONCE (async DMA) + biases
  {
    const char* src = (const char*)wpack;
    char* dst = (char*)sW;
#pragma unroll
    for (int i = 0; i < 11; ++i) {
      const int c = i * 4 + wv;
      gload_lds16(src + c * 1024 + lane * 16, dst + c * 1024);
    }
  }
  if (tid < 128) sB1[tid] = be1[tid];
  else if (tid < 192) sB2[tid - 128] = be2[tid - 128];
  else if (tid < 224) sB3[tid - 192] = be3[tid - 192];

  int tile = blockIdx.x;
  us8 ra1[2], ra2[2];      // atom bf16 frags (raw)
  float4 rb[2][2];         // bond f32 raw
  int ia1n[2], ia2n[2];    // indices for NEXT tile

  // ---- prologue: gather tile0; indices for tile0+G
#pragma unroll
  for (int t = 0; t < 2; ++t) {
    const int e = tile * 128 + esub + t * 16;
    const int ia1 = a1p[e], ia2 = a2p[e];
    ra1[t] = *(const us8*)(atoms_bf + (size_t)ia1 * 32 + q * 8);
    ra2[t] = *(const us8*)(atoms_bf + (size_t)ia2 * 32 + q * 8);
    const float* bp = bonds + (size_t)e * 32 + q * 8;
    rb[t][0] = *(const float4*)(bp);
    rb[t][1] = *(const float4*)(bp + 4);
  }
  {
    int tn = tile + EGRID; if (tn >= ETILES) tn = tile;
#pragma unroll
    for (int t = 0; t < 2; ++t) {
      const int e = tn * 128 + esub + t * 16;
      ia1n[t] = a1p[e]; ia2n[t] = a2p[e];
    }
  }
  __syncthreads();   // weights + biases staged

  for (; tile < ETILES; tile += EGRID) {
    // ---- convert current frags (frees ra/rb)
    bfrag8 xb0[2], xb1[2], xb2[2];
#pragma unroll
    for (int t = 0; t < 2; ++t) {
      xb0[t] = as_frag(ra1[t]);
      xb1[t] = as_frag(ra2[t]);
      xb2[t] = pack8(rb[t][0], rb[t][1]);
    }
    // ---- issue next tile's gathers (indices already resident), then next-next indices
    const int tn = (tile + EGRID < ETILES) ? tile + EGRID : tile;
#pragma unroll
    for (int t = 0; t < 2; ++t) {
      ra1[t] = *(const us8*)(atoms_bf + (size_t)ia1n[t] * 32 + q * 8);
      ra2[t] = *(const us8*)(atoms_bf + (size_t)ia2n[t] * 32 + q * 8);
      const int e = tn * 128 + esub + t * 16;
      const float* bp = bonds + (size_t)e * 32 + q * 8;
      rb[t][0] = *(const float4*)(bp);
      rb[t][1] = *(const float4*)(bp + 4);
    }
    {
      int tnn = tile + 2 * EGRID; if (tnn >= ETILES) tnn = tn;
#pragma unroll
      for (int t = 0; t < 2; ++t) {
        const int e = tnn * 128 + esub + t * 16;
        ia1n[t] = a1p[e]; ia2n[t] = a2p[e];
      }
    }

    // ---- GEMM1: h1^T[128][16x2] = We1^T[128x96] @ x^T ----
#pragma unroll
    for (int rt = 0; rt < 8; ++rt) {
      const unsigned short* wa = &sW[(q * 128 + rt * 16 + cl) * 8];
      bfrag8 w0 = *(const bfrag8*)(wa);
      bfrag8 w1 = *(const bfrag8*)(wa + 4096);
      bfrag8 w2 = *(const bfrag8*)(wa + 8192);
      f32x4 acc[2];
      acc[0] = (f32x4){0.f, 0.f, 0.f, 0.f};
      acc[1] = (f32x4){0.f, 0.f, 0.f, 0.f};
#pragma unroll
      for (int t = 0; t < 2; ++t) {
        acc[t] = mfma16(w0, xb0[t], acc[t]);
        acc[t] = mfma16(w1, xb1[t], acc[t]);
        acc[t] = mfma16(w2, xb2[t], acc[t]);
      }
      const int c0 = rt * 16 + q * 4;
#pragma unroll
      for (int t = 0; t < 2; ++t) {
        uint2 hv = pk4(fmaxf(acc[t][0] + sB1[c0 + 0], 0.f),
                       fmaxf(acc[t][1] + sB1[c0 + 1], 0.f),
                       fmaxf(acc[t][2] + sB1[c0 + 2], 0.f),
                       fmaxf(acc[t][3] + sB1[c0 + 3], 0.f));
        *(uint2*)&sH1[(esub + t * 16) * 136 + c0] = hv;
      }
    }
    __syncthreads();   // h1 complete

    // ---- GEMM2: h2^T[64][16x2] = We2^T[64x128] @ h1^T ----
    bfrag8 hb[4][2];
#pragma unroll
    for (int t = 0; t < 2; ++t) {
      const unsigned short* hr = &sH1[(esub + t * 16) * 136 + q * 8];
#pragma unroll
      for (int ks = 0; ks < 4; ++ks) hb[ks][t] = *(const bfrag8*)(hr + ks * 32);
    }
    __syncthreads();   // h1 reads done -> safe to overwrite as h2

    unsigned short* sH2 = sH1;   // stride 72
#pragma unroll
    for (int rt = 0; rt < 4; ++rt) {
      f32x4 acc[2];
      acc[0] = (f32x4){0.f, 0.f, 0.f, 0.f};
      acc[1] = (f32x4){0.f, 0.f, 0.f, 0.f};
#pragma unroll
      for (int ks = 0; ks < 4; ++ks) {
        bfrag8 w = *(const bfrag8*)&sW[12288 + ks * 2048 + (q * 64 + rt * 16 + cl) * 8];
#pragma unroll
        for (int t = 0; t < 2; ++t) acc[t] = mfma16(w, hb[ks][t], acc[t]);
      }
      const int c0 = rt * 16 + q * 4;
#pragma unroll
      for (int t = 0; t < 2; ++t) {
        uint2 hv = pk4(fmaxf(acc[t][0] + sB2[c0 + 0], 0.f),
                       fmaxf(acc[t][1] + sB2[c0 + 1], 0.f),
                       fmaxf(acc[t][2] + sB2[c0 + 2], 0.f),
                       fmaxf(acc[t][3] + sB2[c0 + 3], 0.f));
        *(uint2*)&sH2[(esub + t * 16) * 72 + c0] = hv;
      }
    }
    __syncthreads();   // h2 complete

    // ---- GEMM3: out^T[32][16x2] = We3^T[32x64] @ h2^T ----
    bfrag8 gb0[2], gb1[2];
#pragma unroll
    for (int t = 0; t < 2; ++t) {
      const unsigned short* hr = &sH2[(esub + t * 16) * 72 + q * 8];
      gb0[t] = *(const bfrag8*)(hr);
      gb1[t] = *(const bfrag8*)(hr + 32);
    }
#pragma unroll
    for (int rt = 0; rt < 2; ++rt) {
      bfrag8 w0 = *(const bfrag8*)&sW[20480 + (q * 32 + rt * 16 + cl) * 8];
      bfrag8 w1 = *(const bfrag8*)&sW[20480 + 1024 + (q * 32 + rt * 16 + cl) * 8];
      const int c0 = rt * 16 + q * 4;
#pragma unroll
      for (int t = 0; t < 2; ++t) {
        f32x4 acc = {0.f, 0.f, 0.f, 0.f};
        acc = mfma16(w0, gb0[t], acc);
        acc = mfma16(w1, gb1[t], acc);
        const int e = tile * 128 + esub + t * 16;
        float4 o;
        o.x = acc[0] + sB3[c0 + 0];
        o.y = acc[1] + sB3[c0 + 1];
        o.z = acc[2] + sB3[c0 + 2];
        o.w = acc[3] + sB3[c0 + 3];
        *(float4*)(new_bonds + (size_t)e * 32 + c0) = o;
      }
    }
    __syncthreads();   // gb reads done -> next tile may overwrite sH1/sH2
  }
}

// ---------------- Gather-mean: 8 threads/node, no LDS, high occupancy ----------------
__global__ __launch_bounds__(256, 4) void gather_mean(
    const int* __restrict__ off, const int* __restrict__ csr,
    const float* __restrict__ new_bonds, float* __restrict__ mean_f32) {
  const int tid = blockIdx.x * 256 + threadIdx.x;   // grid covers NN*8 exactly
  const int n = tid >> 3, sl = tid & 7;             // 16B slice per thread
  const int o0 = off[n], o1 = off[n + 1];
  float4 s0 = {0.f, 0.f, 0.f, 0.f}, s1 = {0.f, 0.f, 0.f, 0.f};
  int i = o0;
  for (; i + 1 < o1; i += 2) {                      // unroll-2: 2 float4 in flight
    const int ea = csr[i], eb = csr[i + 1];
    float4 a = *(const float4*)(new_bonds + (size_t)ea * 32 + sl * 4);
    float4 b = *(const float4*)(new_bonds + (size_t)eb * 32 + sl * 4);
    s0.x += a.x; s0.y += a.y; s0.z += a.z; s0.w += a.w;
    s1.x += b.x; s1.y += b.y; s1.z += b.z; s1.w += b.w;
  }
  if (i < o1) {
    const int ea = csr[i];
    float4 a = *(const float4*)(new_bonds + (size_t)ea * 32 + sl * 4);
    s0.x += a.x; s0.y += a.y; s0.z += a.z; s0.w += a.w;
  }
  const float inv = 1.0f / fmaxf((float)(o1 - o0), 1.0f);
  float4 m;
  m.x = (s0.x + s1.x) * inv;
  m.y = (s0.y + s1.y) * inv;
  m.z = (s0.z + s1.z) * inv;
  m.w = (s0.w + s1.w) * inv;
  *(float4*)(mean_f32 + (size_t)n * 32 + sl * 4) = m;
}

// ---------------- Node MLP: persistent, 64 nodes/tile, streaming inputs -------
__global__ __launch_bounds__(256, 4) void node_mlp(
    const unsigned short* __restrict__ atoms_bf,
    const float* __restrict__ bv1, const float* __restrict__ bv2, const float* __restrict__ bv3,
    const unsigned short* __restrict__ wpack,
    const float* __restrict__ mean_f32, float* __restrict__ new_atoms) {
  __shared__ unsigned short sW[18432];          // Wv1p[8192] Wv2p[8192] Wv3p[2048]
  __shared__ float sB1[128], sB2[64], sB3[32];
  __shared__ unsigned short sV[64 * 72];        // v_in [64][64] pad->72; reused as h2
  __shared__ unsigned short sH1[64 * 136];

  const int tid = threadIdx.x;
  const int lane = tid & 63, wv = tid >> 6;
  const int cl = lane & 15, q = lane >> 4;
  const int nl = tid >> 2, l4 = tid & 3;

  {
    const uint4* src = (const uint4*)wpack;
    uint4* dst = (uint4*)sW;
#pragma unroll
    for (int i = 0; i < 9; ++i) dst[tid + i * 256] = src[tid + i * 256];
  }
  if (tid < 128) sB1[tid] = bv1[tid];
  if (tid < 64) sB2[tid] = bv2[tid];
  if (tid < 32) sB3[tid] = bv3[tid];

  for (int n0 = blockIdx.x * 64; n0 < NN; n0 += NGRID * 64) {
    __syncthreads();   // weights staged / previous tile's LDS reads complete

    // stage v tile: cols [0,32) = mean (f32 -> bf16), [32,64) = atoms (bf16 copy)
    {
      const int n = n0 + nl;
      if (n < NN) {
        if (l4 < 2) {
          const float* sp = mean_f32 + (size_t)n * 32 + l4 * 16;
          float4 a = *(const float4*)(sp);
          float4 b = *(const float4*)(sp + 4);
          float4 c = *(const float4*)(sp + 8);
          float4 d = *(const float4*)(sp + 12);
          uint4 o0, o1;
          o0.x = pk2(a.x, a.y); o0.y = pk2(a.z, a.w);
          o0.z = pk2(b.x, b.y); o0.w = pk2(b.z, b.w);
          o1.x = pk2(c.x, c.y); o1.y = pk2(c.z, c.w);
          o1.z = pk2(d.x, d.y); o1.w = pk2(d.z, d.w);
          *(uint4*)&sV[nl * 72 + l4 * 16] = o0;
          *(uint4*)&sV[nl * 72 + l4 * 16 + 8] = o1;
        } else {
          const unsigned short* ap = atoms_bf + (size_t)n * 32 + (l4 - 2) * 16;
          *(us8*)&sV[nl * 72 + 32 + (l4 - 2) * 16] = *(const us8*)(ap);
          *(us8*)&sV[nl * 72 + 32 + (l4 - 2) * 16 + 8] = *(const us8*)(ap + 8);
        }
      } else {
        us8 z = {0, 0, 0, 0, 0, 0, 0, 0};
        *(us8*)&sV[nl * 72 + l4 * 16] = z;
        *(us8*)&sV[nl * 72 + l4 * 16 + 8] = z;
      }
    }
    __syncthreads();

    const int nt = wv * 16;
    const int ng = n0 + nt + cl;

    // ---- GEMM1: K=64 ----
    bfrag8 vb0 = *(const bfrag8*)&sV[(nt + cl) * 72 + q * 8];
    bfrag8 vb1 = *(const bfrag8*)&sV[(nt + cl) * 72 + 32 + q * 8];
#pragma unroll
    for (int rt = 0; rt < 8; ++rt) {
      f32x4 acc = {0.f, 0.f, 0.f, 0.f};
      acc = mfma16(*(const bfrag8*)&sW[(q * 128 + rt * 16 + cl) * 8], vb0, acc);
      acc = mfma16(*(const bfrag8*)&sW[4096 + (q * 128 + rt * 16 + cl) * 8], vb1, acc);
      const int c0 = rt * 16 + q * 4;
      uint2 hv = pk4(fmaxf(acc[0] + sB1[c0 + 0], 0.f),
                     fmaxf(acc[1] + sB1[c0 + 1], 0.f),
                     fmaxf(acc[2] + sB1[c0 + 2], 0.f),
                     fmaxf(acc[3] + sB1[c0 + 3], 0.f));
      *(uint2*)&sH1[(nt + cl) * 136 + c0] = hv;
    }
    __syncthreads();

    // ---- GEMM2: K=128 ----
    bfrag8 hb[4];
    {
      const unsigned short* hr = &sH1[(nt + cl) * 136 + q * 8];
#pragma unroll
      for (int ks = 0; ks < 4; ++ks) hb[ks] = *(const bfrag8*)(hr + ks * 32);
    }
    __syncthreads();   // h1 reads done -> overwrite sV as h2
#pragma unroll
    for (int rt = 0; rt < 4; ++rt) {
      f32x4 acc = {0.f, 0.f, 0.f, 0.f};
#pragma unroll
      for (int ks = 0; ks < 4; ++ks)
        acc = mfma16(*(const bfrag8*)&sW[8192 + ks * 2048 + (q * 64 + rt * 16 + cl) * 8], hb[ks], acc);
      const int c0 = rt * 16 + q * 4;
      uint2 hv = pk4(fmaxf(acc[0] + sB2[c0 + 0], 0.f),
                     fmaxf(acc[1] + sB2[c0 + 1], 0.f),
                     fmaxf(acc[2] + sB2[c0 + 2], 0.f),
                     fmaxf(acc[3] + sB2[c0 + 3], 0.f));
      *(uint2*)&sV[(nt + cl) * 72 + c0] = hv;   // reuse sV as h2
    }
    __syncthreads();

    // ---- GEMM3: K=64, no relu ----
    bfrag8 gb0 = *(const bfrag8*)&sV[(nt + cl) * 72 + q * 8];
    bfrag8 gb1 = *(const bfrag8*)&sV[(nt + cl) * 72 + 32 + q * 8];
    if (ng < NN) {
      float* outp = new_atoms + (size_t)ng * 32;
#pragma unroll
      for (int rt = 0; rt < 2; ++rt) {
        f32x4 acc = {0.f, 0.f, 0.f, 0.f};
        acc = mfma16(*(const bfrag8*)&sW[16384 + (q * 32 + rt * 16 + cl) * 8], gb0, acc);
        acc = mfma16(*(const bfrag8*)&sW[16384 + 1024 + (q * 32 + rt * 16 + cl) * 8], gb1, acc);
        const int c0 = rt * 16 + q * 4;
        float4 o;
        o.x = acc[0] + sB3[c0 + 0];
        o.y = acc[1] + sB3[c0 + 1];
        o.z = acc[2] + sB3[c0 + 2];
        o.w = acc[3] + sB3[c0 + 3];
        *(float4*)(outp + c0) = o;
      }
    }
  }
}

extern "C" void kernel_launch(void* const* d_in, const int* in_sizes, int n_in,
                              void* d_out, int out_size, void* d_ws, size_t ws_size,
                              hipStream_t stream) {
  const float* bonds = (const float*)d_in[0];
  const int* a1 = (const int*)d_in[1];
  const int* a2 = (const int*)d_in[2];
  const float* atoms = (const float*)d_in[3];
  const float* We1 = (const float*)d_in[4];
  const float* be1 = (const float*)d_in[5];
  const float* We2 = (const float*)d_in[6];
  const float* be2 = (const float*)d_in[7];
  const float* We3 = (const float*)d_in[8];
  const float* be3 = (const float*)d_in[9];
  const float* Wv1 = (const float*)d_in[10];
  const float* bv1 = (const float*)d_in[11];
  const float* Wv2 = (const float*)d_in[12];
  const float* bv2 = (const float*)d_in[13];
  const float* Wv3 = (const float*)d_in[14];
  const float* bv3 = (const float*)d_in[15];

  float* out = (float*)d_out;
  float* new_atoms = out;                       // [NN*32]; pre-final use: mean_f32 scratch
  float* new_bonds = out + (size_t)NN * 32;     // [NE*32]

  char* ws = (char*)d_ws;
  int* cnt    = (int*)(ws + 0);                 // [NN], reused as fill cursor
  int* off    = (int*)(ws + 400000);            // [NN+1]
  int* bsum   = (int*)(ws + 800016);            // [512]
  unsigned short* wp = (unsigned short*)(ws + 802064);        // packed bf16 weights (81920 B)
  int* csr    = (int*)(ws + 883984);            // [NE] (6.4 MB)
  unsigned short* atoms_bf = (unsigned short*)(ws + 7283984); // [NN*32] bf16 (6.4 MB)

  hipMemsetAsync(cnt, 0, (size_t)NN * 4, stream);

  cvt_atoms<<<3125, 256, 0, stream>>>(atoms, atoms_bf);

  pack_w<<<48, 256, 0, stream>>>(We1, wp + 0, 96, 128);
  pack_w<<<32, 256, 0, stream>>>(We2, wp + 12288, 128, 64);
  pack_w<<<8, 256, 0, stream>>>(We3, wp + 20480, 64, 32);
  pack_w<<<32, 256, 0, stream>>>(Wv1, wp + 22528, 64, 128);
  pack_w<<<32, 256, 0, stream>>>(Wv2, wp + 30720, 128, 64);
  pack_w<<<8, 256, 0, stream>>>(Wv3, wp + 38912, 64, 32);

  // CSR build
  count_k<<<(NE + 255) / 256, 256, 0, stream>>>(a2, cnt);
  scan_blocks<<<NB_SCAN, 256, 0, stream>>>(cnt, off, bsum);
  scan_bsum<<<1, 512, 0, stream>>>(bsum);
  scan_finalize<<<NB_SCAN, 256, 0, stream>>>(off, bsum, cnt);   // cursor := cnt
  fill_csr<<<(NE + 255) / 256, 256, 0, stream>>>(a2, cnt, csr);

  edge_kernel<<<EGRID, 256, 0, stream>>>(bonds, a1, a2, atoms_bf, be1, be2, be3, wp,
                                         new_bonds);
  gather_mean<<<NN * 8 / 256, 256, 0, stream>>>(off, csr, new_bonds, new_atoms);
  node_mlp<<<NGRID, 256, 0, stream>>>(atoms_bf, bv1, bv2, bv3, wp + 22528,
                                      new_atoms /*mean in*/, new_atoms /*out*/);
}

// Round 7
// 394.660 us; speedup vs baseline: 2.0583x; 1.0853x over previous
//
#include <hip/hip_runtime.h>
#include <hip/hip_bf16.h>

#define NN 100000
#define NE 1600000
#define NB_SCAN 391   // ceil(NN/256)
#define ETILES 12500  // NE/128
#define EGRID 512
#define NGRID 1024

typedef __attribute__((ext_vector_type(8))) short bfrag8;   // 8 bf16 (4 VGPRs) MFMA operand
typedef __attribute__((ext_vector_type(4))) float f32x4;    // MFMA accumulator
typedef __attribute__((ext_vector_type(8))) unsigned short us8;
typedef __attribute__((ext_vector_type(4))) unsigned int u32x4;

__device__ __forceinline__ unsigned short f2bf(float f) {
  unsigned int u = __float_as_uint(f);
  u += 0x7fffu + ((u >> 16) & 1u);   // RNE
  return (unsigned short)(u >> 16);
}

// packed 2x f32 -> 2x bf16 in one u32 (no builtin on gfx950 -> inline asm, RNE)
__device__ __forceinline__ unsigned int pk2(float a, float b) {
  unsigned int r;
  asm("v_cvt_pk_bf16_f32 %0, %1, %2" : "=v"(r) : "v"(a), "v"(b));
  return r;
}

__device__ __forceinline__ uint2 pk4(float v0, float v1, float v2, float v3) {
  return make_uint2(pk2(v0, v1), pk2(v2, v3));
}

__device__ __forceinline__ bfrag8 pack8(float4 a, float4 b) {
  union { u32x4 u; bfrag8 f; } c;
  c.u[0] = pk2(a.x, a.y); c.u[1] = pk2(a.z, a.w);
  c.u[2] = pk2(b.x, b.y); c.u[3] = pk2(b.z, b.w);
  return c.f;
}

__device__ __forceinline__ bfrag8 as_frag(us8 v) {
  union { us8 u; bfrag8 f; } c;
  c.u = v;
  return c.f;
}

__device__ __forceinline__ float bl(unsigned int u) { return __uint_as_float(u << 16); }
__device__ __forceinline__ float bh(unsigned int u) { return __uint_as_float(u & 0xffff0000u); }

__device__ __forceinline__ f32x4 mfma16(bfrag8 a, bfrag8 b, f32x4 c) {
  return __builtin_amdgcn_mfma_f32_16x16x32_bf16(a, b, c, 0, 0, 0);
}

__device__ __forceinline__ void gload_lds16(const void* g, void* l) {
  __builtin_amdgcn_global_load_lds(
      (const __attribute__((address_space(1))) unsigned int*)g,
      (__attribute__((address_space(3))) unsigned int*)l, 16, 0, 0);
}

// ---------------- prep: cvt_atoms + count + pack_w in ONE launch ----------------
__global__ void prep(const float* __restrict__ atoms, unsigned short* __restrict__ atoms_bf,
                     const int* __restrict__ a2, int* __restrict__ cnt,
                     const float* __restrict__ We1, const float* __restrict__ We2,
                     const float* __restrict__ We3, const float* __restrict__ Wv1,
                     const float* __restrict__ Wv2, const float* __restrict__ Wv3,
                     unsigned short* __restrict__ wp) {
  const int b = blockIdx.x, tid = threadIdx.x;
  if (b < 3125) {                       // cvt_atoms: NN*32/4 = 800000 float4
    const int i = b * 256 + tid;
    float4 v = *(const float4*)(atoms + (size_t)i * 4);
    *(uint2*)(atoms_bf + (size_t)i * 4) = pk4(v.x, v.y, v.z, v.w);
  } else if (b < 3125 + 6250) {         // count
    const int e = (b - 3125) * 256 + tid;
    if (e < NE) atomicAdd(&cnt[a2[e]], 1);
  } else {                              // pack_w over flat table (40960 elems)
    const int i = (b - 9375) * 256 + tid;
    const float* src; int base, K, N;
    if (i < 12288)      { src = We1; base = 0;     K = 96;  N = 128; }
    else if (i < 20480) { src = We2; base = 12288; K = 128; N = 64;  }
    else if (i < 22528) { src = We3; base = 20480; K = 64;  N = 32;  }
    else if (i < 30720) { src = Wv1; base = 22528; K = 64;  N = 128; }
    else if (i < 38912) { src = Wv2; base = 30720; K = 128; N = 64;  }
    else                { src = Wv3; base = 38912; K = 64;  N = 32;  }
    const int il = i - base;
    const int j = il & 7, gc = il >> 3;
    const int c = gc % N, g = gc / N;
    wp[i] = f2bf(src[(g * 8 + j) * N + c]);
    (void)K;
  }
}

// ---------------- CSR construction ----------------
__global__ void scan_blocks(const int* __restrict__ cnt, int* __restrict__ off,
                            int* __restrict__ bsum) {
  __shared__ int s[256];
  const int t = threadIdx.x;
  const int idx = blockIdx.x * 256 + t;
  int v = (idx < NN) ? cnt[idx] : 0;
  s[t] = v;
  __syncthreads();
  for (int d = 1; d < 256; d <<= 1) {
    int x = (t >= d) ? s[t - d] : 0;
    __syncthreads();
    s[t] += x;
    __syncthreads();
  }
  if (idx < NN) off[idx] = s[t] - v;          // exclusive within block
  if (t == 255) bsum[blockIdx.x] = s[255];
}

// finalize: each block computes its own base = sum(bsum[0..b-1]) (391 ints, cheap)
__global__ void scan_finalize(int* __restrict__ off, const int* __restrict__ bsum,
                              int* __restrict__ cursor) {
  __shared__ int red[256];
  const int b = blockIdx.x, t = threadIdx.x;
  int s = 0;
  for (int k = t; k < b; k += 256) s += bsum[k];
  red[t] = s;
  __syncthreads();
  for (int d = 128; d > 0; d >>= 1) {
    if (t < d) red[t] += red[t + d];
    __syncthreads();
  }
  const int base = red[0];
  const int idx = b * 256 + t;
  if (idx < NN) {
    int o = off[idx] + base;
    off[idx] = o;
    cursor[idx] = o;
  }
  if (idx == 0) off[NN] = NE;
}

// mode 1: pos[e] = slot (coalesced write); mode 0: csr[slot] = e (scattered)
__global__ void fill_k(const int* __restrict__ a2, int* __restrict__ cursor,
                       int* __restrict__ buf, int mode) {
  int e = blockIdx.x * 256 + threadIdx.x;
  if (e < NE) {
    int p = atomicAdd(&cursor[a2[e]], 1);
    if (mode) buf[e] = p;
    else buf[p] = e;
  }
}

// ---------------- Edge kernel: persistent, 128 edges/tile, 1-tile pipeline ----------------
__global__ __launch_bounds__(256, 2) void edge_kernel(
    const float* __restrict__ bonds, const int* __restrict__ a1p, const int* __restrict__ a2p,
    const unsigned short* __restrict__ atoms_bf,
    const float* __restrict__ be1, const float* __restrict__ be2, const float* __restrict__ be3,
    const unsigned short* __restrict__ wpack,
    float* __restrict__ new_bonds,
    const int* __restrict__ pos, unsigned short* __restrict__ nb_bf) {
  __shared__ unsigned short sW[22528];          // We1p[12288] We2p[8192] We3p[2048] = 45056 B
  __shared__ float sB1[128], sB2[64], sB3[32];
  __shared__ unsigned short sH1[128 * 136];     // h1 [128][128] pad->136; aliased as h2 [128][72]

  const int tid = threadIdx.x;
  const int lane = tid & 63, wv = tid >> 6;
  const int cl = lane & 15, q = lane >> 4;
  const int esub = wv * 32 + cl;                // + t*16

  // ---- stage weights ONCE (async DMA) + biases
  {
    const char* src = (const char*)wpack;
    char* dst = (char*)sW;
#pragma unroll
    for (int i = 0; i < 11; ++i) {
      const int c = i * 4 + wv;
      gload_lds16(src + c * 1024 + lane * 16, dst + c * 1024);
    }
  }
  if (tid < 128) sB1[tid] = be1[tid];
  else if (tid < 192) sB2[tid - 128] = be2[tid - 128];
  else if (tid < 224) sB3[tid - 192] = be3[tid - 192];

  int tile = blockIdx.x;
  us8 ra1[2], ra2[2];      // atom bf16 frags (raw)
  float4 rb[2][2];         // bond f32 raw
  int ia1n[2], ia2n[2];    // indices for NEXT tile

  // ---- prologue: gather tile0; indices for tile0+G
#pragma unroll
  for (int t = 0; t < 2; ++t) {
    const int e = tile * 128 + esub + t * 16;
    const int ia1 = a1p[e], ia2 = a2p[e];
    ra1[t] = *(const us8*)(atoms_bf + (size_t)ia1 * 32 + q * 8);
    ra2[t] = *(const us8*)(atoms_bf + (size_t)ia2 * 32 + q * 8);
    const float* bp = bonds + (size_t)e * 32 + q * 8;
    rb[t][0] = *(const float4*)(bp);
    rb[t][1] = *(const float4*)(bp + 4);
  }
  {
    int tn = tile + EGRID; if (tn >= ETILES) tn = tile;
#pragma unroll
    for (int t = 0; t < 2; ++t) {
      const int e = tn * 128 + esub + t * 16;
      ia1n[t] = a1p[e]; ia2n[t] = a2p[e];
    }
  }
  __syncthreads();   // weights + biases staged

  for (; tile < ETILES; tile += EGRID) {
    // ---- convert current frags (frees ra/rb)
    bfrag8 xb0[2], xb1[2], xb2[2];
#pragma unroll
    for (int t = 0; t < 2; ++t) {
      xb0[t] = as_frag(ra1[t]);
      xb1[t] = as_frag(ra2[t]);
      xb2[t] = pack8(rb[t][0], rb[t][1]);
    }
    // ---- CSR slots for current tile (streamed; latency hidden by GEMMs)
    int posc[2] = {0, 0};
    if (nb_bf) {
#pragma unroll
      for (int t = 0; t < 2; ++t) posc[t] = pos[tile * 128 + esub + t * 16];
    }
    // ---- issue next tile's gathers (indices already resident), then next-next indices
    const int tn = (tile + EGRID < ETILES) ? tile + EGRID : tile;
#pragma unroll
    for (int t = 0; t < 2; ++t) {
      ra1[t] = *(const us8*)(atoms_bf + (size_t)ia1n[t] * 32 + q * 8);
      ra2[t] = *(const us8*)(atoms_bf + (size_t)ia2n[t] * 32 + q * 8);
      const int e = tn * 128 + esub + t * 16;
      const float* bp = bonds + (size_t)e * 32 + q * 8;
      rb[t][0] = *(const float4*)(bp);
      rb[t][1] = *(const float4*)(bp + 4);
    }
    {
      int tnn = tile + 2 * EGRID; if (tnn >= ETILES) tnn = tn;
#pragma unroll
      for (int t = 0; t < 2; ++t) {
        const int e = tnn * 128 + esub + t * 16;
        ia1n[t] = a1p[e]; ia2n[t] = a2p[e];
      }
    }

    // ---- GEMM1: h1^T[128][16x2] = We1^T[128x96] @ x^T ----
#pragma unroll
    for (int rt = 0; rt < 8; ++rt) {
      const unsigned short* wa = &sW[(q * 128 + rt * 16 + cl) * 8];
      bfrag8 w0 = *(const bfrag8*)(wa);
      bfrag8 w1 = *(const bfrag8*)(wa + 4096);
      bfrag8 w2 = *(const bfrag8*)(wa + 8192);
      f32x4 acc[2];
      acc[0] = (f32x4){0.f, 0.f, 0.f, 0.f};
      acc[1] = (f32x4){0.f, 0.f, 0.f, 0.f};
#pragma unroll
      for (int t = 0; t < 2; ++t) {
        acc[t] = mfma16(w0, xb0[t], acc[t]);
        acc[t] = mfma16(w1, xb1[t], acc[t]);
        acc[t] = mfma16(w2, xb2[t], acc[t]);
      }
      const int c0 = rt * 16 + q * 4;
#pragma unroll
      for (int t = 0; t < 2; ++t) {
        uint2 hv = pk4(fmaxf(acc[t][0] + sB1[c0 + 0], 0.f),
                       fmaxf(acc[t][1] + sB1[c0 + 1], 0.f),
                       fmaxf(acc[t][2] + sB1[c0 + 2], 0.f),
                       fmaxf(acc[t][3] + sB1[c0 + 3], 0.f));
        *(uint2*)&sH1[(esub + t * 16) * 136 + c0] = hv;
      }
    }
    __syncthreads();   // h1 complete

    // ---- GEMM2: h2^T[64][16x2] = We2^T[64x128] @ h1^T ----
    bfrag8 hb[4][2];
#pragma unroll
    for (int t = 0; t < 2; ++t) {
      const unsigned short* hr = &sH1[(esub + t * 16) * 136 + q * 8];
#pragma unroll
      for (int ks = 0; ks < 4; ++ks) hb[ks][t] = *(const bfrag8*)(hr + ks * 32);
    }
    __syncthreads();   // h1 reads done -> safe to overwrite as h2

    unsigned short* sH2 = sH1;   // stride 72
#pragma unroll
    for (int rt = 0; rt < 4; ++rt) {
      f32x4 acc[2];
      acc[0] = (f32x4){0.f, 0.f, 0.f, 0.f};
      acc[1] = (f32x4){0.f, 0.f, 0.f, 0.f};
#pragma unroll
      for (int ks = 0; ks < 4; ++ks) {
        bfrag8 w = *(const bfrag8*)&sW[12288 + ks * 2048 + (q * 64 + rt * 16 + cl) * 8];
#pragma unroll
        for (int t = 0; t < 2; ++t) acc[t] = mfma16(w, hb[ks][t], acc[t]);
      }
      const int c0 = rt * 16 + q * 4;
#pragma unroll
      for (int t = 0; t < 2; ++t) {
        uint2 hv = pk4(fmaxf(acc[t][0] + sB2[c0 + 0], 0.f),
                       fmaxf(acc[t][1] + sB2[c0 + 1], 0.f),
                       fmaxf(acc[t][2] + sB2[c0 + 2], 0.f),
                       fmaxf(acc[t][3] + sB2[c0 + 3], 0.f));
        *(uint2*)&sH2[(esub + t * 16) * 72 + c0] = hv;
      }
    }
    __syncthreads();   // h2 complete

    // ---- GEMM3: out^T[32][16x2] = We3^T[32x64] @ h2^T ----
    bfrag8 gb0[2], gb1[2];
#pragma unroll
    for (int t = 0; t < 2; ++t) {
      const unsigned short* hr = &sH2[(esub + t * 16) * 72 + q * 8];
      gb0[t] = *(const bfrag8*)(hr);
      gb1[t] = *(const bfrag8*)(hr + 32);
    }
#pragma unroll
    for (int rt = 0; rt < 2; ++rt) {
      bfrag8 w0 = *(const bfrag8*)&sW[20480 + (q * 32 + rt * 16 + cl) * 8];
      bfrag8 w1 = *(const bfrag8*)&sW[20480 + 1024 + (q * 32 + rt * 16 + cl) * 8];
      const int c0 = rt * 16 + q * 4;
#pragma unroll
      for (int t = 0; t < 2; ++t) {
        f32x4 acc = {0.f, 0.f, 0.f, 0.f};
        acc = mfma16(w0, gb0[t], acc);
        acc = mfma16(w1, gb1[t], acc);
        const int e = tile * 128 + esub + t * 16;
        float4 o;
        o.x = acc[0] + sB3[c0 + 0];
        o.y = acc[1] + sB3[c0 + 1];
        o.z = acc[2] + sB3[c0 + 2];
        o.w = acc[3] + sB3[c0 + 3];
        *(float4*)(new_bonds + (size_t)e * 32 + c0) = o;
        if (nb_bf) {   // bf16 copy into CSR slot (streaming-aggregation feed)
          *(uint2*)(nb_bf + (size_t)posc[t] * 32 + c0) =
              make_uint2(pk2(o.x, o.y), pk2(o.z, o.w));
        }
      }
    }
    __syncthreads();   // gb reads done -> next tile may overwrite sH1/sH2
  }
}

// ---------------- Gather (fast): sequential segmented mean over CSR-ordered bf16 rows ----
__global__ __launch_bounds__(256, 8) void gather_seq(
    const int* __restrict__ off, const unsigned short* __restrict__ nb_bf,
    unsigned short* __restrict__ mean_bf) {
  const int gt = blockIdx.x * 256 + threadIdx.x;   // NN*8
  const int n = gt >> 3, sl = gt & 7;              // 8 B slice (4 bf16) per thread
  const int o0 = off[n], o1 = off[n + 1];
  const int deg = o1 - o0;
  float s0 = 0.f, s1 = 0.f, s2 = 0.f, s3 = 0.f;
  const unsigned short* p = nb_bf + (size_t)o0 * 32 + sl * 4;
  int i = 0;
  for (; i + 1 < deg; i += 2) {
    uint2 a = *(const uint2*)(p);
    uint2 b = *(const uint2*)(p + 32);
    p += 64;
    s0 += bl(a.x) + bl(b.x); s1 += bh(a.x) + bh(b.x);
    s2 += bl(a.y) + bl(b.y); s3 += bh(a.y) + bh(b.y);
  }
  if (i < deg) {
    uint2 a = *(const uint2*)(p);
    s0 += bl(a.x); s1 += bh(a.x); s2 += bl(a.y); s3 += bh(a.y);
  }
  const float inv = 1.0f / fmaxf((float)deg, 1.0f);
  *(uint2*)(mean_bf + (size_t)n * 32 + sl * 4) =
      make_uint2(pk2(s0 * inv, s1 * inv), pk2(s2 * inv, s3 * inv));
}

// ---------------- Gather (fallback): random rows via csr ----------------
__global__ __launch_bounds__(256, 8) void gather_rand(
    const int* __restrict__ off, const int* __restrict__ csr,
    const float* __restrict__ new_bonds, float* __restrict__ mean_f32) {
  const int tid = blockIdx.x * 256 + threadIdx.x;   // NN*8
  const int n = tid >> 3, sl = tid & 7;             // 16 B slice per thread
  const int o0 = off[n], o1 = off[n + 1];
  float4 s0 = {0.f, 0.f, 0.f, 0.f}, s1 = {0.f, 0.f, 0.f, 0.f};
  int i = o0;
  for (; i + 1 < o1; i += 2) {
    const int ea = csr[i], eb = csr[i + 1];
    float4 a = *(const float4*)(new_bonds + (size_t)ea * 32 + sl * 4);
    float4 b = *(const float4*)(new_bonds + (size_t)eb * 32 + sl * 4);
    s0.x += a.x; s0.y += a.y; s0.z += a.z; s0.w += a.w;
    s1.x += b.x; s1.y += b.y; s1.z += b.z; s1.w += b.w;
  }
  if (i < o1) {
    const int ea = csr[i];
    float4 a = *(const float4*)(new_bonds + (size_t)ea * 32 + sl * 4);
    s0.x += a.x; s0.y += a.y; s0.z += a.z; s0.w += a.w;
  }
  const float inv = 1.0f / fmaxf((float)(o1 - o0), 1.0f);
  float4 m;
  m.x = (s0.x + s1.x) * inv;
  m.y = (s0.y + s1.y) * inv;
  m.z = (s0.z + s1.z) * inv;
  m.w = (s0.w + s1.w) * inv;
  *(float4*)(mean_f32 + (size_t)n * 32 + sl * 4) = m;
}

// ---------------- Node MLP: persistent, 64 nodes/tile, streaming inputs -------
// MODE 1: mean_src = bf16[NN*32]; MODE 0: mean_src = f32[NN*32]
template <int MODE>
__global__ __launch_bounds__(256, 4) void node_mlp(
    const unsigned short* __restrict__ atoms_bf,
    const float* __restrict__ bv1, const float* __restrict__ bv2, const float* __restrict__ bv3,
    const unsigned short* __restrict__ wpack,
    const void* __restrict__ mean_src, float* __restrict__ new_atoms) {
  __shared__ unsigned short sW[18432];          // Wv1p[8192] Wv2p[8192] Wv3p[2048]
  __shared__ float sB1[128], sB2[64], sB3[32];
  __shared__ unsigned short sV[64 * 72];        // v_in [64][64] pad->72; reused as h2
  __shared__ unsigned short sH1[64 * 136];

  const int tid = threadIdx.x;
  const int lane = tid & 63, wv = tid >> 6;
  const int cl = lane & 15, q = lane >> 4;
  const int nl = tid >> 2, l4 = tid & 3;

  {
    const uint4* src = (const uint4*)wpack;
    uint4* dst = (uint4*)sW;
#pragma unroll
    for (int i = 0; i < 9; ++i) dst[tid + i * 256] = src[tid + i * 256];
  }
  if (tid < 128) sB1[tid] = bv1[tid];
  if (tid < 64) sB2[tid] = bv2[tid];
  if (tid < 32) sB3[tid] = bv3[tid];

  for (int n0 = blockIdx.x * 64; n0 < NN; n0 += NGRID * 64) {
    __syncthreads();   // weights staged / previous tile's LDS reads complete

    // stage v tile: cols [0,32) = mean, [32,64) = atoms (bf16 copy)
    {
      const int n = n0 + nl;
      if (n < NN) {
        if (l4 < 2) {
          if (MODE == 1) {
            const unsigned short* mp = (const unsigned short*)mean_src + (size_t)n * 32 + l4 * 16;
            *(us8*)&sV[nl * 72 + l4 * 16] = *(const us8*)(mp);
            *(us8*)&sV[nl * 72 + l4 * 16 + 8] = *(const us8*)(mp + 8);
          } else {
            const float* sp = (const float*)mean_src + (size_t)n * 32 + l4 * 16;
            float4 a = *(const float4*)(sp);
            float4 b = *(const float4*)(sp + 4);
            float4 c = *(const float4*)(sp + 8);
            float4 d = *(const float4*)(sp + 12);
            uint4 o0, o1;
            o0.x = pk2(a.x, a.y); o0.y = pk2(a.z, a.w);
            o0.z = pk2(b.x, b.y); o0.w = pk2(b.z, b.w);
            o1.x = pk2(c.x, c.y); o1.y = pk2(c.z, c.w);
            o1.z = pk2(d.x, d.y); o1.w = pk2(d.z, d.w);
            *(uint4*)&sV[nl * 72 + l4 * 16] = o0;
            *(uint4*)&sV[nl * 72 + l4 * 16 + 8] = o1;
          }
        } else {
          const unsigned short* ap = atoms_bf + (size_t)n * 32 + (l4 - 2) * 16;
          *(us8*)&sV[nl * 72 + 32 + (l4 - 2) * 16] = *(const us8*)(ap);
          *(us8*)&sV[nl * 72 + 32 + (l4 - 2) * 16 + 8] = *(const us8*)(ap + 8);
        }
      } else {
        us8 z = {0, 0, 0, 0, 0, 0, 0, 0};
        *(us8*)&sV[nl * 72 + l4 * 16] = z;
        *(us8*)&sV[nl * 72 + l4 * 16 + 8] = z;
      }
    }
    __syncthreads();

    const int nt = wv * 16;
    const int ng = n0 + nt + cl;

    // ---- GEMM1: K=64 ----
    bfrag8 vb0 = *(const bfrag8*)&sV[(nt + cl) * 72 + q * 8];
    bfrag8 vb1 = *(const bfrag8*)&sV[(nt + cl) * 72 + 32 + q * 8];
#pragma unroll
    for (int rt = 0; rt < 8; ++rt) {
      f32x4 acc = {0.f, 0.f, 0.f, 0.f};
      acc = mfma16(*(const bfrag8*)&sW[(q * 128 + rt * 16 + cl) * 8], vb0, acc);
      acc = mfma16(*(const bfrag8*)&sW[4096 + (q * 128 + rt * 16 + cl) * 8], vb1, acc);
      const int c0 = rt * 16 + q * 4;
      uint2 hv = pk4(fmaxf(acc[0] + sB1[c0 + 0], 0.f),
                     fmaxf(acc[1] + sB1[c0 + 1], 0.f),
                     fmaxf(acc[2] + sB1[c0 + 2], 0.f),
                     fmaxf(acc[3] + sB1[c0 + 3], 0.f));
      *(uint2*)&sH1[(nt + cl) * 136 + c0] = hv;
    }
    __syncthreads();

    // ---- GEMM2: K=128 ----
    bfrag8 hb[4];
    {
      const unsigned short* hr = &sH1[(nt + cl) * 136 + q * 8];
#pragma unroll
      for (int ks = 0; ks < 4; ++ks) hb[ks] = *(const bfrag8*)(hr + ks * 32);
    }
    __syncthreads();   // h1 reads done -> overwrite sV as h2
#pragma unroll
    for (int rt = 0; rt < 4; ++rt) {
      f32x4 acc = {0.f, 0.f, 0.f, 0.f};
#pragma unroll
      for (int ks = 0; ks < 4; ++ks)
        acc = mfma16(*(const bfrag8*)&sW[8192 + ks * 2048 + (q * 64 + rt * 16 + cl) * 8], hb[ks], acc);
      const int c0 = rt * 16 + q * 4;
      uint2 hv = pk4(fmaxf(acc[0] + sB2[c0 + 0], 0.f),
                     fmaxf(acc[1] + sB2[c0 + 1], 0.f),
                     fmaxf(acc[2] + sB2[c0 + 2], 0.f),
                     fmaxf(acc[3] + sB2[c0 + 3], 0.f));
      *(uint2*)&sV[(nt + cl) * 72 + c0] = hv;   // reuse sV as h2
    }
    __syncthreads();

    // ---- GEMM3: K=64, no relu ----
    bfrag8 gb0 = *(const bfrag8*)&sV[(nt + cl) * 72 + q * 8];
    bfrag8 gb1 = *(const bfrag8*)&sV[(nt + cl) * 72 + 32 + q * 8];
    if (ng < NN) {
      float* outp = new_atoms + (size_t)ng * 32;
#pragma unroll
      for (int rt = 0; rt < 2; ++rt) {
        f32x4 acc = {0.f, 0.f, 0.f, 0.f};
        acc = mfma16(*(const bfrag8*)&sW[16384 + (q * 32 + rt * 16 + cl) * 8], gb0, acc);
        acc = mfma16(*(const bfrag8*)&sW[16384 + 1024 + (q * 32 + rt * 16 + cl) * 8], gb1, acc);
        const int c0 = rt * 16 + q * 4;
        float4 o;
        o.x = acc[0] + sB3[c0 + 0];
        o.y = acc[1] + sB3[c0 + 1];
        o.z = acc[2] + sB3[c0 + 2];
        o.w = acc[3] + sB3[c0 + 3];
        *(float4*)(outp + c0) = o;
      }
    }
  }
}

extern "C" void kernel_launch(void* const* d_in, const int* in_sizes, int n_in,
                              void* d_out, int out_size, void* d_ws, size_t ws_size,
                              hipStream_t stream) {
  const float* bonds = (const float*)d_in[0];
  const int* a1 = (const int*)d_in[1];
  const int* a2 = (const int*)d_in[2];
  const float* atoms = (const float*)d_in[3];
  const float* We1 = (const float*)d_in[4];
  const float* be1 = (const float*)d_in[5];
  const float* We2 = (const float*)d_in[6];
  const float* be2 = (const float*)d_in[7];
  const float* We3 = (const float*)d_in[8];
  const float* be3 = (const float*)d_in[9];
  const float* Wv1 = (const float*)d_in[10];
  const float* bv1 = (const float*)d_in[11];
  const float* Wv2 = (const float*)d_in[12];
  const float* bv2 = (const float*)d_in[13];
  const float* Wv3 = (const float*)d_in[14];
  const float* bv3 = (const float*)d_in[15];

  float* out = (float*)d_out;
  float* new_atoms = out;                       // [NN*32]; fallback: also mean_f32 scratch
  float* new_bonds = out + (size_t)NN * 32;     // [NE*32]

  char* ws = (char*)d_ws;
  int* cnt    = (int*)(ws + 0);                 // [NN], reused as fill cursor
  int* off    = (int*)(ws + 400000);            // [NN+1]
  int* bsum   = (int*)(ws + 800016);            // [512]
  unsigned short* wp = (unsigned short*)(ws + 802064);        // packed bf16 weights (81920 B)
  int* poscsr = (int*)(ws + 883984);            // [NE] pos (fast) or csr (fallback)
  unsigned short* atoms_bf = (unsigned short*)(ws + 7283984); // [NN*32] bf16 (6.4 MB)
  unsigned short* mean_bf  = (unsigned short*)(ws + 13683984); // [NN*32] bf16 (fast only)
  unsigned short* nb_bf    = (unsigned short*)(ws + 20083984); // [NE*32] bf16 (fast only)

  const int fast = (ws_size >= (size_t)122483984) ? 1 : 0;

  hipMemsetAsync(cnt, 0, (size_t)NN * 4, stream);

  prep<<<9535, 256, 0, stream>>>(atoms, atoms_bf, a2, cnt,
                                 We1, We2, We3, Wv1, Wv2, Wv3, wp);

  scan_blocks<<<NB_SCAN, 256, 0, stream>>>(cnt, off, bsum);
  scan_finalize<<<NB_SCAN, 256, 0, stream>>>(off, bsum, cnt);   // cursor := cnt
  fill_k<<<(NE + 255) / 256, 256, 0, stream>>>(a2, cnt, poscsr, fast);

  edge_kernel<<<EGRID, 256, 0, stream>>>(bonds, a1, a2, atoms_bf, be1, be2, be3, wp,
                                         new_bonds, poscsr, fast ? nb_bf : nullptr);

  if (fast) {
    gather_seq<<<NN * 8 / 256, 256, 0, stream>>>(off, nb_bf, mean_bf);
    node_mlp<1><<<NGRID, 256, 0, stream>>>(atoms_bf, bv1, bv2, bv3, wp + 22528,
                                           mean_bf, new_atoms);
  } else {
    gather_rand<<<NN * 8 / 256, 256, 0, stream>>>(off, poscsr, new_bonds, new_atoms);
    node_mlp<0><<<NGRID, 256, 0, stream>>>(atoms_bf, bv1, bv2, bv3, wp + 22528,
                                           new_atoms, new_atoms);
  }
}